// Round 14
// baseline (1413.562 us; speedup 1.0000x reference)
//
#include <hip/hip_runtime.h>
#include <hip/hip_bf16.h>
#include <math.h>

#define B_ 16
#define L_ 3072
#define D_ 512
#define CH_ (B_ * D_)   // 8192 channels
#define TOPK_ 40
#define NCAND_ 64       // candidate slots per channel
#define CFLOOR_ 52      // candidate count floor (>= RFN_ always)
#define RFN_ 24         // candidates refined exactly in f64 (rounds 3/4 proven)

typedef unsigned short ushort_t;
typedef unsigned int uint_t;
typedef __attribute__((ext_vector_type(8))) short bh8;   // 8 bf16 (4 VGPRs)
typedef __attribute__((ext_vector_type(4))) float f4;    // 4 f32 acc
typedef __attribute__((ext_vector_type(4))) int i4;      // 16B vector

__device__ __forceinline__ uint_t cvt_pk_bf16(float a, float b) {
  uint_t r;
  asm("v_cvt_pk_bf16_f32 %0, %1, %2" : "=v"(r) : "v"(a), "v"(b));
  return r;  // lo ushort = bf16(a), hi ushort = bf16(b)
}

// LDS byte-address swizzles (involutions; preserve 16B alignment)
__device__ __forceinline__ int swzq(int b) { return b ^ (((b >> 7) & 3) << 4); }
__device__ __forceinline__ int swzk(int b) { return b ^ (((b >> 9) & 7) << 4); }

// ---------------------------------------------------------------------------
// f32-VALU projection GEMM for Q AND K in one dispatch (z-split), 128x128
// tile, 8x8 per thread. BK=16 panels (round-14): LDS 17.9 KB -> 7-8 blocks/CU
// (was 4 at BK=32) — occupancy was the binding constraint (round-13 lesson:
// T14 reg-prefetch HURT at 4 blocks/CU; reverted to stage-then-compute).
// Per-output product order ascending j with the same fmaf chain ->
// Qc/Kc BIT-IDENTICAL to rounds 4/7/12/13.
// LDS layout idx = 140*kk + row + 4*(row>>5): injective (offset<140), 2-way
// bank conflicts on b128 reads (free).
// ---------------------------------------------------------------------------
__device__ __forceinline__ int xidx(int kk, int row) {
  return kk * 140 + row + ((row >> 5) << 2);
}

__global__ __launch_bounds__(256) void proj_qk_kernel(const float* __restrict__ Xq,
                                                      const float* __restrict__ Xk,
                                                      const float* __restrict__ Wq_,
                                                      const float* __restrict__ Wk_,
                                                      const float* __restrict__ bq_,
                                                      const float* __restrict__ bk_,
                                                      float* __restrict__ Pq,
                                                      float* __restrict__ Pk,
                                                      int nbb) {
  __shared__ float Xs[2240];   // 16 kk-slices * 140 stride
  __shared__ float Ws[2240];
  const int z = blockIdx.z;
  const bool isK = (z >= nbb);
  const float* X    = isK ? Xk : Xq;
  const float* W    = isK ? Wk_ : Wq_;
  const float* bias = isK ? bk_ : bq_;
  float* P          = isK ? Pk : Pq;
  const int b  = isK ? (z - nbb) : z;
  const int t0 = blockIdx.x * 128;
  const int i0 = blockIdx.y * 128;
  const int tid = threadIdx.x;
  const int tx = tid & 15, ty = tid >> 4;
  const int row = tid >> 1, jh = (tid & 1) * 8;

  const float* gxb = X + ((size_t)b * L_ + t0 + row) * D_ + jh;
  const float* gwb = W + (size_t)(i0 + row) * D_ + jh;

  float acc[8][8];
#pragma unroll
  for (int r = 0; r < 8; ++r)
#pragma unroll
    for (int s = 0; s < 8; ++s) acc[r][s] = 0.0f;

  for (int j0 = 0; j0 < D_; j0 += 16) {
    {
      const float* gx = gxb + j0;
      const float* gw = gwb + j0;
      float4 x0 = *(const float4*)(gx + 0);
      float4 x1 = *(const float4*)(gx + 4);
      float4 w0 = *(const float4*)(gw + 0);
      float4 w1 = *(const float4*)(gw + 4);
      Xs[xidx(jh + 0, row)] = x0.x;
      Xs[xidx(jh + 1, row)] = x0.y;
      Xs[xidx(jh + 2, row)] = x0.z;
      Xs[xidx(jh + 3, row)] = x0.w;
      Xs[xidx(jh + 4, row)] = x1.x;
      Xs[xidx(jh + 5, row)] = x1.y;
      Xs[xidx(jh + 6, row)] = x1.z;
      Xs[xidx(jh + 7, row)] = x1.w;
      Ws[xidx(jh + 0, row)] = w0.x;
      Ws[xidx(jh + 1, row)] = w0.y;
      Ws[xidx(jh + 2, row)] = w0.z;
      Ws[xidx(jh + 3, row)] = w0.w;
      Ws[xidx(jh + 4, row)] = w1.x;
      Ws[xidx(jh + 5, row)] = w1.y;
      Ws[xidx(jh + 6, row)] = w1.z;
      Ws[xidx(jh + 7, row)] = w1.w;
    }
    __syncthreads();
#pragma unroll 4
    for (int kk = 0; kk < 16; ++kk) {
      float a8[8], w8[8];
      *(float4*)&a8[0] = *(const float4*)&Xs[xidx(kk, 8 * ty)];
      *(float4*)&a8[4] = *(const float4*)&Xs[xidx(kk, 8 * ty) + 4];
      *(float4*)&w8[0] = *(const float4*)&Ws[xidx(kk, 8 * tx)];
      *(float4*)&w8[4] = *(const float4*)&Ws[xidx(kk, 8 * tx) + 4];
#pragma unroll
      for (int r = 0; r < 8; ++r)
#pragma unroll
        for (int s = 0; s < 8; ++s)
          acc[r][s] = fmaf(a8[r], w8[s], acc[r][s]);
    }
    __syncthreads();
  }
#pragma unroll
  for (int s = 0; s < 8; ++s) {
    const int i = i0 + 8 * tx + s;
    const float bia = bias[i];
    float* dst = P + (size_t)(b * D_ + i) * L_ + t0 + 8 * ty;
    float4 v0 = { acc[0][s] + bia, acc[1][s] + bia, acc[2][s] + bia, acc[3][s] + bia };
    float4 v1 = { acc[4][s] + bia, acc[5][s] + bia, acc[6][s] + bia, acc[7][s] + bia };
    *(float4*)dst = v0;
    *(float4*)(dst + 4) = v1;
  }
}

// ---------------------------------------------------------------------------
// MFMA GEMM, 128x128 tile, 4 waves — LINEAR path (V proj, out GEMM).
// NPASS=1 (plain bf16): round-4/8 PROVEN config (absmax floor).
// ---------------------------------------------------------------------------
template <int NPASS, int BK, int ST>
__device__ __forceinline__ void stage_rows(const float* __restrict__ g0,
                                           ushort_t* __restrict__ Hh,
                                           ushort_t* __restrict__ Hl,
                                           int tid) {
  const int row = tid >> 1;
  const int cb = (tid & 1) * (BK / 2);
  const float* g = g0 + (size_t)row * 512 + cb;
  ushort_t* lh = Hh + row * ST + cb;
  ushort_t* ll = Hl + row * ST + cb;
#pragma unroll
  for (int p = 0; p < BK / 8; ++p) {
    float4 v = *(const float4*)(g + 4 * p);
    uint_t h01 = cvt_pk_bf16(v.x, v.y);
    uint_t h23 = cvt_pk_bf16(v.z, v.w);
    *(uint2*)(lh + 4 * p) = make_uint2(h01, h23);
    if (NPASS == 3) {
      float x0 = __builtin_bit_cast(float, h01 << 16);
      float x1 = __builtin_bit_cast(float, h01 & 0xFFFF0000u);
      float x2 = __builtin_bit_cast(float, h23 << 16);
      float x3 = __builtin_bit_cast(float, h23 & 0xFFFF0000u);
      uint_t l01 = cvt_pk_bf16(v.x - x0, v.y - x1);
      uint_t l23 = cvt_pk_bf16(v.z - x2, v.w - x3);
      *(uint2*)(ll + 4 * p) = make_uint2(l01, l23);
    }
  }
}

template <int NPASS, bool ATR, bool BIAS_N>
__global__ __launch_bounds__(256) void gemm_mfma(const float* __restrict__ Ap,
                                                 const float* __restrict__ Bp,
                                                 const float* __restrict__ bias,
                                                 float* __restrict__ Cp,
                                                 long aBS, long bBS, long cBS,
                                                 int cld) {
  constexpr int BK = (NPASS == 3) ? 32 : 64;
  constexpr int ST = (NPASS == 3) ? 40 : 72;
  __shared__ ushort_t Ah[128 * ST];
  __shared__ ushort_t Bh[128 * ST];
  __shared__ ushort_t Al[(NPASS == 3) ? 128 * ST : 8];
  __shared__ ushort_t Bl[(NPASS == 3) ? 128 * ST : 8];

  const float* Asrc = Ap + (size_t)blockIdx.z * aBS;
  const float* Bsrc = Bp + (size_t)blockIdx.z * bBS;
  float* Cb = Cp + (size_t)blockIdx.z * cBS;
  const int n0 = blockIdx.x * 128, m0 = blockIdx.y * 128;
  const int tid = threadIdx.x;
  const int lane = tid & 63, w = tid >> 6;
  const int wr = w >> 1, wc = w & 1;
  const int lj = lane & 15, lg = lane >> 4;

  f4 acc[4][4];
#pragma unroll
  for (int fm = 0; fm < 4; ++fm)
#pragma unroll
    for (int fn = 0; fn < 4; ++fn) acc[fm][fn] = (f4){0.f, 0.f, 0.f, 0.f};

  for (int kc = 0; kc < 512; kc += BK) {
    if (!ATR) {
      stage_rows<NPASS, BK, ST>(Asrc + (size_t)m0 * 512 + kc, Ah, Al, tid);
    } else {
      constexpr int TPC = 256 / BK;
      constexpr int TC  = 128 / TPC;
      const int jl = tid / TPC, ts = tid % TPC;
      const float* g = Asrc + (size_t)(kc + jl) * L_ + m0 + ts * TC;
#pragma unroll
      for (int p = 0; p < TC / 4; ++p) {
        float4 v = *(const float4*)(g + 4 * p);
        uint_t h01 = cvt_pk_bf16(v.x, v.y);
        uint_t h23 = cvt_pk_bf16(v.z, v.w);
        int t = ts * TC + 4 * p;
        Ah[(t + 0) * ST + jl] = (ushort_t)(h01 & 0xFFFFu);
        Ah[(t + 1) * ST + jl] = (ushort_t)(h01 >> 16);
        Ah[(t + 2) * ST + jl] = (ushort_t)(h23 & 0xFFFFu);
        Ah[(t + 3) * ST + jl] = (ushort_t)(h23 >> 16);
        if (NPASS == 3) {
          float x0 = __builtin_bit_cast(float, h01 << 16);
          float x1 = __builtin_bit_cast(float, h01 & 0xFFFF0000u);
          float x2 = __builtin_bit_cast(float, h23 << 16);
          float x3 = __builtin_bit_cast(float, h23 & 0xFFFF0000u);
          uint_t l01 = cvt_pk_bf16(v.x - x0, v.y - x1);
          uint_t l23 = cvt_pk_bf16(v.z - x2, v.w - x3);
          Al[(t + 0) * ST + jl] = (ushort_t)(l01 & 0xFFFFu);
          Al[(t + 1) * ST + jl] = (ushort_t)(l01 >> 16);
          Al[(t + 2) * ST + jl] = (ushort_t)(l23 & 0xFFFFu);
          Al[(t + 3) * ST + jl] = (ushort_t)(l23 >> 16);
        }
      }
    }
    stage_rows<NPASS, BK, ST>(Bsrc + (size_t)n0 * 512 + kc, Bh, Bl, tid);
    __syncthreads();

#pragma unroll
    for (int ks = 0; ks < BK / 32; ++ks) {
      const int kk = ks * 32 + 8 * lg;
      bh8 af[4], bf[4];
#pragma unroll
      for (int f = 0; f < 4; ++f)
        af[f] = *(const bh8*)&Ah[(64 * wr + 16 * f + lj) * ST + kk];
#pragma unroll
      for (int f = 0; f < 4; ++f)
        bf[f] = *(const bh8*)&Bh[(64 * wc + 16 * f + lj) * ST + kk];
#pragma unroll
      for (int fm = 0; fm < 4; ++fm)
#pragma unroll
        for (int fn = 0; fn < 4; ++fn)
          acc[fm][fn] = __builtin_amdgcn_mfma_f32_16x16x32_bf16(af[fm], bf[fn],
                                                                acc[fm][fn], 0, 0, 0);
      if (NPASS == 3) {
        bh8 bl_[4];
#pragma unroll
        for (int f = 0; f < 4; ++f)
          bl_[f] = *(const bh8*)&Bl[(64 * wc + 16 * f + lj) * ST + kk];
#pragma unroll
        for (int fm = 0; fm < 4; ++fm)
#pragma unroll
          for (int fn = 0; fn < 4; ++fn)
            acc[fm][fn] = __builtin_amdgcn_mfma_f32_16x16x32_bf16(af[fm], bl_[fn],
                                                                  acc[fm][fn], 0, 0, 0);
        bh8 al_[4];
#pragma unroll
        for (int f = 0; f < 4; ++f)
          al_[f] = *(const bh8*)&Al[(64 * wr + 16 * f + lj) * ST + kk];
#pragma unroll
        for (int fm = 0; fm < 4; ++fm)
#pragma unroll
          for (int fn = 0; fn < 4; ++fn)
            acc[fm][fn] = __builtin_amdgcn_mfma_f32_16x16x32_bf16(al_[fm], bf[fn],
                                                                  acc[fm][fn], 0, 0, 0);
      }
    }
    __syncthreads();
  }

#pragma unroll
  for (int fm = 0; fm < 4; ++fm) {
    const int mrow = m0 + 64 * wr + 16 * fm + 4 * lg;
#pragma unroll
    for (int fn = 0; fn < 4; ++fn) {
      const int ncol = n0 + 64 * wc + 16 * fn + lj;
      const float bn = BIAS_N ? bias[ncol] : 0.0f;
#pragma unroll
      for (int r = 0; r < 4; ++r) {
        float val = acc[fm][fn][r] + (BIAS_N ? bn : bias[mrow + r]);
        Cb[(size_t)(mrow + r) * cld + ncol] = val;
      }
    }
  }
}

// ---------------------------------------------------------------------------
// FUSED MFMA autocorrelation + candidate selection + f64 refinement + top-40.
// (Round-12 structure, PASSED at absmax floor — unchanged.)
// ---------------------------------------------------------------------------
template <int P>
__device__ __forceinline__ void ac_kloop(const char* __restrict__ qb,
                                         const char* __restrict__ kb,
                                         const int* __restrict__ aswz,
                                         int bbyte, f4 acc[4]) {
#pragma unroll
  for (int it = 0; it < 12; ++it) {
    const int t512 = it * 512;
    const int b512 = bbyte + t512;
    const int msk = ((b512 >> 9) & 7) << 4;
    const int e0 = b512 ^ msk;
    const int e1 = (b512 + 64) ^ msk;
#pragma unroll
    for (int u = 0; u < 8; ++u) {
      i4 w0 = *(const i4*)(qb + (aswz[2 * u] + t512));
      i4 w1 = *(const i4*)(qb + (aswz[2 * u + 1] + t512));
      uint_t w[8] = { (uint_t)w0.x, (uint_t)w0.y, (uint_t)w0.z, (uint_t)w0.w,
                      (uint_t)w1.x, (uint_t)w1.y, (uint_t)w1.z, (uint_t)w1.w };
      const int bb = ((u & 1) ? e1 : e0) + 128 * (u >> 1);
      bh8 Bf = *(const bh8*)(kb + bb);
#pragma unroll
      for (int e = 0; e < 4; ++e) {
        const int ro = (e >> 1) + 2 * P;
        const int sh = (e & 1) * 16;
        uint_t a0v = (uint_t)((((unsigned long long)w[ro + 1] << 32) | w[ro + 0]) >> sh);
        uint_t a1v = (uint_t)((((unsigned long long)w[ro + 2] << 32) | w[ro + 1]) >> sh);
        uint_t a2v = (uint_t)((((unsigned long long)w[ro + 3] << 32) | w[ro + 2]) >> sh);
        uint_t a3v = (uint_t)((((unsigned long long)w[ro + 4] << 32) | w[ro + 3]) >> sh);
        i4 ai = { (int)a0v, (int)a1v, (int)a2v, (int)a3v };
        bh8 Af = __builtin_bit_cast(bh8, ai);
        acc[e] = __builtin_amdgcn_mfma_f32_16x16x32_bf16(Af, Bf, acc[e], 0, 0, 0);
      }
    }
  }
}

__global__ __launch_bounds__(256) void cand_refine_kernel(const float* __restrict__ Q,
                                                          const float* __restrict__ K,
                                                          double* __restrict__ top_vals,
                                                          int* __restrict__ top_idx,
                                                          int c0) {
  // phase A: [0,6912) q bf16 (swz) | [6912,18688) k bf16 (swz)
  // post-kloop: ac f32 at [0,12288)
  // phase C:   qf f32 [0,12292) (incl. qf[L] pad) | kf f32 [12304,24592)
  __shared__ __align__(16) char smem[24608];
  __shared__ float redf[8];
  __shared__ int   redi[4];
  __shared__ int   cnt_s;
  __shared__ float cv[NCAND_];
  __shared__ int   ci[NCAND_];
  __shared__ float sv[TOPK_];
  __shared__ int   si[TOPK_];
  __shared__ double refv[RFN_];
  char* kbase = smem + 6912;
  float* ac_s = (float*)smem;
  const int c = blockIdx.x;
  const int tid = threadIdx.x;
  const float* Qp = Q + (size_t)c * L_;
  const float* Kp = K + (size_t)c * L_;

  // ---- Phase A staging: f32 -> bf16 (cvt_pk), swizzled stores ----
  for (int x8 = tid; x8 < 432; x8 += 256) {
    int x = x8 * 8; int src = x - (x >= L_ ? L_ : 0);
    float4 f0 = *(const float4*)(Qp + src);
    float4 f1 = *(const float4*)(Qp + src + 4);
    i4 pk = { (int)cvt_pk_bf16(f0.x, f0.y), (int)cvt_pk_bf16(f0.z, f0.w),
              (int)cvt_pk_bf16(f1.x, f1.y), (int)cvt_pk_bf16(f1.z, f1.w) };
    *(i4*)(smem + swzq(16 * x8)) = pk;
  }
  for (int x8 = tid; x8 < 736; x8 += 256) {
    int x = x8 * 8; int src = x - 2816 + (x < 2816 ? L_ : 0);
    float4 f0 = *(const float4*)(Kp + src);
    float4 f1 = *(const float4*)(Kp + src + 4);
    i4 pk = { (int)cvt_pk_bf16(f0.x, f0.y), (int)cvt_pk_bf16(f0.z, f0.w),
              (int)cvt_pk_bf16(f1.x, f1.y), (int)cvt_pk_bf16(f1.z, f1.w) };
    *(i4*)(kbase + swzk(16 * x8)) = pk;
  }
  __syncthreads();

  const int lane = tid & 63, fg = tid >> 6;
  const int lg = lane >> 4, lj = lane & 15;
  const int abyte = 16 * lg + 32 * lj + 16 * (fg >> 1);
  const int jvalid = (lj < 12) ? 1 : 0;
  const int bbyte = 5632 + 16 * lg - (jvalid ? 512 * lj : 0);

  int aswz[16];
#pragma unroll
  for (int u = 0; u < 8; ++u) {
    aswz[2 * u]     = swzq(abyte + 64 * u);
    aswz[2 * u + 1] = swzq(abyte + 64 * u + 16);
  }

  f4 acc[4];
#pragma unroll
  for (int e = 0; e < 4; ++e) acc[e] = (f4){0.f, 0.f, 0.f, 0.f};

  if (fg & 1) ac_kloop<1>(smem, kbase, aswz, bbyte, acc);
  else        ac_kloop<0>(smem, kbase, aswz, bbyte, acc);

  __syncthreads();   // all kloop q/k reads done before ac overlays them

  if (jvalid) {
#pragma unroll
    for (int e = 0; e < 4; ++e) {
      int f = 4 * fg + e;
#pragma unroll
      for (int r = 0; r < 4; ++r) {
        int g = f + 16 * (4 * lg + r);      // fine lag in [0,256)
        ac_s[lj + 12 * g] = acc[e][r];      // tau = g + 256*lj
      }
    }
  }
  __syncthreads();

  float v[12];
#pragma unroll
  for (int it = 0; it < 12; ++it) v[it] = ac_s[tid + 256 * it];

  // block max
  float lm = v[0];
#pragma unroll
  for (int it = 1; it < 12; ++it) lm = fmaxf(lm, v[it]);
  for (int o = 32; o; o >>= 1) lm = fmaxf(lm, __shfl_down(lm, o));
  if ((tid & 63) == 0) redf[tid >> 6] = lm;
  __syncthreads();
  if (tid == 0) redf[4] = fmaxf(fmaxf(redf[0], redf[1]), fmaxf(redf[2], redf[3]));
  __syncthreads();
  const float Tmax = redf[4];

  auto bcount = [&](float T) -> int {
    int lc = 0;
#pragma unroll
    for (int it = 0; it < 12; ++it) lc += (v[it] > T) ? 1 : 0;
    for (int o = 32; o; o >>= 1) lc += __shfl_down(lc, o);
    __syncthreads();
    if ((tid & 63) == 0) redi[tid >> 6] = lc;
    __syncthreads();
    return redi[0] + redi[1] + redi[2] + redi[3];
  };

  float lo = Tmax - 128.0f;
  int cl = bcount(lo);
  for (int wd = 1; wd <= 5 && cl < CFLOOR_; ++wd) {
    lo = Tmax - 128.0f * (float)(1 << wd); cl = bcount(lo);
  }
  float hi = Tmax, T = lo;
  int cT = cl;
  for (int i = 0; i < 26 && cT > NCAND_; ++i) {
    float mid = 0.5f * (lo + hi);
    int cm = bcount(mid);
    if (cm >= CFLOOR_) { lo = mid; T = mid; cT = cm; } else hi = mid;
  }

  if (tid == 0) cnt_s = 0;
  __syncthreads();
#pragma unroll
  for (int it = 0; it < 12; ++it) {
    if (v[it] > T) {
      int pos = atomicAdd(&cnt_s, 1);
      if (pos < NCAND_) {
        int m = tid + 256 * it;
        int g = m / 12, j = m - 12 * g;
        cv[pos] = v[it];
        ci[pos] = g + 256 * j;
      }
    }
  }
  __syncthreads();
  const int cnt = cnt_s < NCAND_ ? cnt_s : NCAND_;

  // ---- Phase B (wave 0: rank-based f32 top-40) || C-staging (waves 1-3) ---
  float* qf = (float*)smem;
  float* kf = (float*)(smem + 12304);
  if (tid >= 64) {
    for (int i = (tid - 64) * 4; i < L_; i += 768) {
      *(float4*)&qf[i] = *(const float4*)(Qp + i);
      *(float4*)&kf[i] = *(const float4*)(Kp + i);
    }
    if (tid == 64) qf[L_] = qf[0];   // circular pad for phase-C pair reads
  } else {
    float vi = (tid < cnt) ? cv[tid] : -1e30f;
    int   ii = (tid < cnt) ? ci[tid] : (1 << 30);
    int rank = 0;
#pragma unroll 8
    for (int j = 0; j < 64; ++j) {
      float vj = __shfl(vi, j);
      int   ij = __shfl(ii, j);
      rank += ((vj > vi) || (vj == vi && ij < ii)) ? 1 : 0;
    }
    if (rank < TOPK_) { sv[rank] = vi; si[rank] = (ii < L_) ? ii : 0; }
  }
  __syncthreads();

  // ---- Phase C: exact f64 ac for top-RFN_, one WAVE per candidate, 2-wide -
  for (int r = fg; r < RFN_; r += 4) {
    const int tau = si[r];
    double a = 0.0;
#pragma unroll 4
    for (int u = 0; u < 24; ++u) {
      int t = 2 * lane + 128 * u;
      int qi = t + tau; qi -= (qi >= L_) ? L_ : 0;
      float q0 = qf[qi], q1 = qf[qi + 1];
      float k0 = kf[t],  k1 = kf[t + 1];
      a = fma((double)q0, (double)k0, a);
      a = fma((double)q1, (double)k1, a);
    }
#pragma unroll
    for (int o = 32; o; o >>= 1) a += __shfl_down(a, o);
    if (lane == 0) refv[r] = a;
  }
  __syncthreads();

  // ---- Phase D: rank-based f64 sort of refined -> ranks 0..RFN_-1;
  //      ranks RFN_..39 from f32 order (rounds 3/4 proven harmless) ----
  double* out_v = top_vals + (size_t)(c0 + c) * TOPK_;
  int*    out_i = top_idx  + (size_t)(c0 + c) * TOPK_;
  if (tid < 64) {
    double dv = (tid < RFN_) ? refv[tid] : -1e300;
    int    di = (tid < RFN_) ? si[tid]   : (1 << 30);
    int rank = 0;
#pragma unroll 8
    for (int j = 0; j < RFN_; ++j) {
      double dj = __shfl(dv, j);
      int    ij = __shfl(di, j);
      rank += ((dj > dv) || (dj == dv && ij < di)) ? 1 : 0;
    }
    if (tid < RFN_) { out_v[rank] = dv; out_i[rank] = di; }
    if (tid >= RFN_ && tid < TOPK_) {
      out_v[tid] = (double)sv[tid];
      out_i[tid] = si[tid];
    }
  }
}

// ---------------------------------------------------------------------------
__global__ __launch_bounds__(256) void shifts_kernel(const int* __restrict__ top_idx,
                                                     int* __restrict__ shifts) {
  const int k = blockIdx.x;
  __shared__ double sred[256];
  double s = 0.0;
  for (int c = threadIdx.x; c < CH_; c += 256) s += (double)top_idx[(size_t)c * TOPK_ + k];
  sred[threadIdx.x] = s;
  __syncthreads();
  for (int o = 128; o > 0; o >>= 1) {
    if (threadIdx.x < o) sred[threadIdx.x] += sred[threadIdx.x + o];
    __syncthreads();
  }
  if (threadIdx.x == 0) shifts[k] = (int)((float)(sred[0] / (double)CH_));
}

__global__ __launch_bounds__(256) void softmax_kernel(const double* __restrict__ top_vals,
                                                      float* __restrict__ weights) {
  const int c = blockIdx.x * 256 + threadIdx.x;
  const double* v = top_vals + (size_t)c * TOPK_;
  double m = v[0];
  for (int k = 1; k < TOPK_; ++k) m = fmax(m, v[k]);
  double sum = 0.0;
  for (int k = 0; k < TOPK_; ++k) sum += exp(v[k] - m);
  double inv = 1.0 / sum;
  for (int k = 0; k < TOPK_; ++k)
    weights[(size_t)c * TOPK_ + k] = (float)(exp(v[k] - m) * inv);
}

// agg[c][t] = sum_k w[c][k] * V[c][(t+shift[k]) mod L], in place.
__global__ __launch_bounds__(256) void agg_kernel(float* __restrict__ Vc,
                                                  const float* __restrict__ weights,
                                                  const int* __restrict__ shifts) {
  const int c = blockIdx.x;
  __shared__ float v_s[L_ + 4];
  __shared__ float w_s[TOPK_];
  __shared__ int   s_s[TOPK_];
  float* row = Vc + (size_t)c * L_;
  for (int i = threadIdx.x * 4; i < L_; i += 1024)
    *(float4*)&v_s[i] = *(const float4*)(row + i);
  if (threadIdx.x < TOPK_) {
    w_s[threadIdx.x] = weights[(size_t)c * TOPK_ + threadIdx.x];
    s_s[threadIdx.x] = shifts[threadIdx.x];
  }
  __syncthreads();
  if (threadIdx.x < 4) v_s[L_ + threadIdx.x] = v_s[threadIdx.x];
  __syncthreads();
  for (int t = threadIdx.x * 4; t < L_; t += 1024) {
    float s0 = 0.f, s1 = 0.f, s2 = 0.f, s3 = 0.f;
#pragma unroll
    for (int k = 0; k < TOPK_; ++k) {
      int idx = t + s_s[k];
      if (idx >= L_) idx -= L_;
      const float w = w_s[k];
      s0 = fmaf(w, v_s[idx],     s0);
      s1 = fmaf(w, v_s[idx + 1], s1);
      s2 = fmaf(w, v_s[idx + 2], s2);
      s3 = fmaf(w, v_s[idx + 3], s3);
    }
    float4 o = { s0, s1, s2, s3 };
    *(float4*)(row + t) = o;
  }
}

// ---------------------------------------------------------------------------
extern "C" void kernel_launch(void* const* d_in, const int* in_sizes, int n_in,
                              void* d_out, int out_size, void* d_ws, size_t ws_size,
                              hipStream_t stream) {
  const float* query = (const float*)d_in[0];
  const float* key   = (const float*)d_in[1];
  const float* value = (const float*)d_in[2];
  const float* Wq = (const float*)d_in[3];
  const float* bq = (const float*)d_in[4];
  const float* Wk = (const float*)d_in[5];
  const float* bk = (const float*)d_in[6];
  const float* Wv = (const float*)d_in[7];
  const float* bvp = (const float*)d_in[8];
  const float* Wo = (const float*)d_in[9];
  const float* bo = (const float*)d_in[10];
  float* out = (float*)d_out;
  char* ws = (char*)d_ws;

  auto al = [](size_t x) { return (x + 255) & ~(size_t)255; };
  size_t off = 0;
  const size_t tv_off = off; off = al(off + (size_t)CH_ * TOPK_ * 8);
  const size_t ti_off = off; off = al(off + (size_t)CH_ * TOPK_ * 4);
  const size_t w_off  = off; off = al(off + (size_t)CH_ * TOPK_ * 4);
  const size_t sh_off = off; off = al(off + (size_t)TOPK_ * 4);
  const size_t small_end = off;                       // ~5.3 MB

  const size_t QK1   = (size_t)D_ * L_ * 4;           // 6.29 MB f32, one batch
  const size_t PBQK  = al(2 * QK1);                   // ~12.6 MB per batch
  const size_t AGG_BYTES    = (size_t)CH_ * L_ * 4;   // 96 MB
  const size_t BOUNCE_BYTES = (size_t)D_ * L_ * 4;    // 6 MB

  int nb; bool bounce;
  if (ws_size >= small_end + AGG_BYTES + PBQK) {
    bounce = false;
    size_t n = (ws_size - small_end - AGG_BYTES) / PBQK;
    nb = (int)(n > 16 ? 16 : n);
  } else {
    bounce = true;
    size_t rem = (ws_size > small_end + BOUNCE_BYTES) ? (ws_size - small_end - BOUNCE_BYTES) : 0;
    size_t n = rem / PBQK; nb = (int)(n > 16 ? 16 : n);
    if (nb < 1) nb = 1;
  }

  double* top_vals = (double*)(ws + tv_off);
  int*    top_idx  = (int*)(ws + ti_off);
  float*  weights  = (float*)(ws + w_off);
  int*    shifts   = (int*)(ws + sh_off);

  float* VcAgg;
  float* bounce_buf = nullptr;
  size_t qk_off;
  if (!bounce) {
    VcAgg = (float*)(ws + small_end);
    qk_off = small_end + al(AGG_BYTES);
  } else {
    bounce_buf = (float*)(ws + small_end);
    qk_off = small_end + al(BOUNCE_BYTES);
    VcAgg = (float*)d_out;
  }
  float* Qc = (float*)(ws + qk_off);
  float* Kc = (float*)(ws + qk_off + al((size_t)nb * QK1));

  dim3 blk(256);
  const long bXS = (long)L_ * D_;   // batch stride of inputs / out
  const long cQS = (long)D_ * L_;   // batch stride of channel-major tensors

  for (int b0 = 0; b0 < B_; b0 += nb) {
    int nbb = (B_ - b0 < nb) ? (B_ - b0) : nb;
    dim3 g(L_ / 128, D_ / 128, 2 * nbb);
    proj_qk_kernel<<<g, blk, 0, stream>>>(query + (size_t)b0 * L_ * D_,
                                          key   + (size_t)b0 * L_ * D_,
                                          Wq, Wk, bq, bk, Qc, Kc, nbb);
    cand_refine_kernel<<<nbb * D_, blk, 0, stream>>>(Qc, Kc, top_vals, top_idx, b0 * D_);
  }
  shifts_kernel<<<TOPK_, blk, 0, stream>>>(top_idx, shifts);
  softmax_kernel<<<CH_ / 256, blk, 0, stream>>>(top_vals, weights);

  {
    dim3 gp(L_ / 128, D_ / 128, B_);
    gemm_mfma<1, false, false><<<gp, blk, 0, stream>>>(
        Wv, value, bvp, VcAgg, 0, bXS, cQS, L_);
  }
  agg_kernel<<<CH_, blk, 0, stream>>>(VcAgg, weights, shifts);

  if (!bounce) {
    dim3 go(D_ / 128, L_ / 128, B_);    // (4, 24, 16)
    gemm_mfma<1, true, true><<<go, blk, 0, stream>>>(
        VcAgg, Wo, bo, out, cQS, 0, bXS, D_);
  } else {
    for (int b = 0; b < B_; ++b) {
      hipMemcpyAsync(bounce_buf, VcAgg + (size_t)b * D_ * L_, BOUNCE_BYTES,
                     hipMemcpyDeviceToDevice, stream);
      dim3 go(D_ / 128, L_ / 128, 1);
      gemm_mfma<1, true, true><<<go, blk, 0, stream>>>(
          bounce_buf, Wo, bo, out + (size_t)b * L_ * D_, 0, 0, 0, D_);
    }
  }
  (void)in_sizes; (void)n_in; (void)out_size;
}

// Round 15
// 1076.534 us; speedup vs baseline: 1.3131x; 1.3131x over previous
//
#include <hip/hip_runtime.h>
#include <hip/hip_bf16.h>
#include <math.h>

#define B_ 16
#define L_ 3072
#define D_ 512
#define CH_ (B_ * D_)   // 8192 channels
#define TOPK_ 40
#define NCAND_ 64       // candidate slots per channel
#define CFLOOR_ 52      // candidate count floor (>= RFN_ always)
#define RFN_ 24         // candidates refined exactly in f64 (rounds 3/4 proven)

typedef unsigned short ushort_t;
typedef unsigned int uint_t;
typedef __attribute__((ext_vector_type(8))) short bh8;   // 8 bf16 (4 VGPRs)
typedef __attribute__((ext_vector_type(4))) float f4;    // 4 f32 acc
typedef __attribute__((ext_vector_type(4))) int i4;      // 16B vector

__device__ __forceinline__ uint_t cvt_pk_bf16(float a, float b) {
  uint_t r;
  asm("v_cvt_pk_bf16_f32 %0, %1, %2" : "=v"(r) : "v"(a), "v"(b));
  return r;  // lo ushort = bf16(a), hi ushort = bf16(b)
}

// LDS byte-address swizzles (involutions; preserve 16B alignment)
__device__ __forceinline__ int swzq(int b) { return b ^ (((b >> 7) & 3) << 4); }
__device__ __forceinline__ int swzk(int b) { return b ^ (((b >> 9) & 7) << 4); }

// ---------------------------------------------------------------------------
// MFMA GEMM, 128x128 tile, 4 waves. C[m][n] = sum_k A[m][k] B[n][k] + bias.
// NPASS=1: plain bf16 (V proj, out GEMM — round-4/8 PROVEN, absmax floor).
// NPASS=6: 3-way split-bf16 (h/m/l, Sterbenz-exact residuals; products
//   hh+hm+mh+mm+hl+lh) -> dropped terms <= 2^-25 -> dP ~1.5e-6, SAME error
//   class as the f32-VALU chain (1.4e-6) which rounds 2-vs-4 proved safe
//   (identical absmax under a 1.4e-6 Qc/Kc perturbation). Used for Q/K.
// ---------------------------------------------------------------------------
template <int NPASS, int BK, int ST>
__device__ __forceinline__ void stage_rows(const float* __restrict__ g0,
                                           ushort_t* __restrict__ Hh,
                                           ushort_t* __restrict__ Hm,
                                           ushort_t* __restrict__ Hl,
                                           int tid) {
  const int row = tid >> 1;
  const int cb = (tid & 1) * (BK / 2);
  const float* g = g0 + (size_t)row * 512 + cb;
  ushort_t* ph = Hh + row * ST + cb;
  ushort_t* pm = Hm + row * ST + cb;
  ushort_t* pl = Hl + row * ST + cb;
#pragma unroll
  for (int p = 0; p < BK / 8; ++p) {
    float4 v = *(const float4*)(g + 4 * p);
    uint_t h01 = cvt_pk_bf16(v.x, v.y);
    uint_t h23 = cvt_pk_bf16(v.z, v.w);
    *(uint2*)(ph + 4 * p) = make_uint2(h01, h23);
    if (NPASS >= 3) {
      float x0 = __builtin_bit_cast(float, h01 << 16);
      float x1 = __builtin_bit_cast(float, h01 & 0xFFFF0000u);
      float x2 = __builtin_bit_cast(float, h23 << 16);
      float x3 = __builtin_bit_cast(float, h23 & 0xFFFF0000u);
      float r0 = v.x - x0, r1 = v.y - x1, r2 = v.z - x2, r3 = v.w - x3;
      uint_t m01 = cvt_pk_bf16(r0, r1);
      uint_t m23 = cvt_pk_bf16(r2, r3);
      if (NPASS == 3) {
        *(uint2*)(pl + 4 * p) = make_uint2(m01, m23);
      } else {  // NPASS == 6: store m, then exact third level l
        *(uint2*)(pm + 4 * p) = make_uint2(m01, m23);
        float y0 = __builtin_bit_cast(float, m01 << 16);
        float y1 = __builtin_bit_cast(float, m01 & 0xFFFF0000u);
        float y2 = __builtin_bit_cast(float, m23 << 16);
        float y3 = __builtin_bit_cast(float, m23 & 0xFFFF0000u);
        uint_t l01 = cvt_pk_bf16(r0 - y0, r1 - y1);
        uint_t l23 = cvt_pk_bf16(r2 - y2, r3 - y3);
        *(uint2*)(pl + 4 * p) = make_uint2(l01, l23);
      }
    }
  }
}

template <int NPASS, bool ATR, bool BIAS_N>
__global__ __launch_bounds__(256) void gemm_mfma(const float* __restrict__ Ap,
                                                 const float* __restrict__ Bp,
                                                 const float* __restrict__ bias,
                                                 float* __restrict__ Cp,
                                                 long aBS, long bBS, long cBS,
                                                 int cld) {
  constexpr int BK = (NPASS == 1) ? 64 : 32;
  constexpr int ST = (NPASS == 1) ? 72 : 40;
  __shared__ ushort_t Ah[128 * ST];
  __shared__ ushort_t Bh[128 * ST];
  __shared__ ushort_t Al[(NPASS >= 3) ? 128 * ST : 8];
  __shared__ ushort_t Bl[(NPASS >= 3) ? 128 * ST : 8];
  __shared__ ushort_t Am[(NPASS == 6) ? 128 * ST : 8];
  __shared__ ushort_t Bm[(NPASS == 6) ? 128 * ST : 8];

  const float* Asrc = Ap + (size_t)blockIdx.z * aBS;
  const float* Bsrc = Bp + (size_t)blockIdx.z * bBS;
  float* Cb = Cp + (size_t)blockIdx.z * cBS;
  const int n0 = blockIdx.x * 128, m0 = blockIdx.y * 128;
  const int tid = threadIdx.x;
  const int lane = tid & 63, w = tid >> 6;
  const int wr = w >> 1, wc = w & 1;
  const int lj = lane & 15, lg = lane >> 4;

  f4 acc[4][4];
#pragma unroll
  for (int fm = 0; fm < 4; ++fm)
#pragma unroll
    for (int fn = 0; fn < 4; ++fn) acc[fm][fn] = (f4){0.f, 0.f, 0.f, 0.f};

  for (int kc = 0; kc < 512; kc += BK) {
    if (!ATR) {
      stage_rows<NPASS, BK, ST>(Asrc + (size_t)m0 * 512 + kc, Ah, Am, Al, tid);
    } else {
      // out-GEMM A-staging (channel-major agg); only instantiated NPASS==1
      constexpr int TPC = 256 / BK;
      constexpr int TC  = 128 / TPC;
      const int jl = tid / TPC, ts = tid % TPC;
      const float* g = Asrc + (size_t)(kc + jl) * L_ + m0 + ts * TC;
#pragma unroll
      for (int p = 0; p < TC / 4; ++p) {
        float4 v = *(const float4*)(g + 4 * p);
        uint_t h01 = cvt_pk_bf16(v.x, v.y);
        uint_t h23 = cvt_pk_bf16(v.z, v.w);
        int t = ts * TC + 4 * p;
        Ah[(t + 0) * ST + jl] = (ushort_t)(h01 & 0xFFFFu);
        Ah[(t + 1) * ST + jl] = (ushort_t)(h01 >> 16);
        Ah[(t + 2) * ST + jl] = (ushort_t)(h23 & 0xFFFFu);
        Ah[(t + 3) * ST + jl] = (ushort_t)(h23 >> 16);
      }
    }
    stage_rows<NPASS, BK, ST>(Bsrc + (size_t)n0 * 512 + kc, Bh, Bm, Bl, tid);
    __syncthreads();

#pragma unroll
    for (int ks = 0; ks < BK / 32; ++ks) {
      const int kk = ks * 32 + 8 * lg;
      bh8 af[4], bf[4];
#pragma unroll
      for (int f = 0; f < 4; ++f)
        af[f] = *(const bh8*)&Ah[(64 * wr + 16 * f + lj) * ST + kk];
#pragma unroll
      for (int f = 0; f < 4; ++f)
        bf[f] = *(const bh8*)&Bh[(64 * wc + 16 * f + lj) * ST + kk];
#pragma unroll
      for (int fm = 0; fm < 4; ++fm)
#pragma unroll
        for (int fn = 0; fn < 4; ++fn)
          acc[fm][fn] = __builtin_amdgcn_mfma_f32_16x16x32_bf16(af[fm], bf[fn],
                                                                acc[fm][fn], 0, 0, 0);
      if (NPASS >= 3) {
        bh8 bl_[4];
#pragma unroll
        for (int f = 0; f < 4; ++f)
          bl_[f] = *(const bh8*)&Bl[(64 * wc + 16 * f + lj) * ST + kk];
        bh8 al_[4];
#pragma unroll
        for (int f = 0; f < 4; ++f)
          al_[f] = *(const bh8*)&Al[(64 * wr + 16 * f + lj) * ST + kk];
        if (NPASS == 3) {
          // 2-way split: hh above, + h*lo + lo*h
#pragma unroll
          for (int fm = 0; fm < 4; ++fm)
#pragma unroll
            for (int fn = 0; fn < 4; ++fn)
              acc[fm][fn] = __builtin_amdgcn_mfma_f32_16x16x32_bf16(af[fm], bl_[fn],
                                                                    acc[fm][fn], 0, 0, 0);
#pragma unroll
          for (int fm = 0; fm < 4; ++fm)
#pragma unroll
            for (int fn = 0; fn < 4; ++fn)
              acc[fm][fn] = __builtin_amdgcn_mfma_f32_16x16x32_bf16(al_[fm], bf[fn],
                                                                    acc[fm][fn], 0, 0, 0);
        } else {
          // NPASS == 6: hm, mh, mm, hl, lh
          bh8 am_[4], bm_[4];
#pragma unroll
          for (int f = 0; f < 4; ++f)
            am_[f] = *(const bh8*)&Am[(64 * wr + 16 * f + lj) * ST + kk];
#pragma unroll
          for (int f = 0; f < 4; ++f)
            bm_[f] = *(const bh8*)&Bm[(64 * wc + 16 * f + lj) * ST + kk];
#pragma unroll
          for (int fm = 0; fm < 4; ++fm)
#pragma unroll
            for (int fn = 0; fn < 4; ++fn)
              acc[fm][fn] = __builtin_amdgcn_mfma_f32_16x16x32_bf16(af[fm], bm_[fn],
                                                                    acc[fm][fn], 0, 0, 0);
#pragma unroll
          for (int fm = 0; fm < 4; ++fm)
#pragma unroll
            for (int fn = 0; fn < 4; ++fn)
              acc[fm][fn] = __builtin_amdgcn_mfma_f32_16x16x32_bf16(am_[fm], bf[fn],
                                                                    acc[fm][fn], 0, 0, 0);
#pragma unroll
          for (int fm = 0; fm < 4; ++fm)
#pragma unroll
            for (int fn = 0; fn < 4; ++fn)
              acc[fm][fn] = __builtin_amdgcn_mfma_f32_16x16x32_bf16(am_[fm], bm_[fn],
                                                                    acc[fm][fn], 0, 0, 0);
#pragma unroll
          for (int fm = 0; fm < 4; ++fm)
#pragma unroll
            for (int fn = 0; fn < 4; ++fn)
              acc[fm][fn] = __builtin_amdgcn_mfma_f32_16x16x32_bf16(af[fm], bl_[fn],
                                                                    acc[fm][fn], 0, 0, 0);
#pragma unroll
          for (int fm = 0; fm < 4; ++fm)
#pragma unroll
            for (int fn = 0; fn < 4; ++fn)
              acc[fm][fn] = __builtin_amdgcn_mfma_f32_16x16x32_bf16(al_[fm], bf[fn],
                                                                    acc[fm][fn], 0, 0, 0);
        }
      }
    }
    __syncthreads();
  }

#pragma unroll
  for (int fm = 0; fm < 4; ++fm) {
    const int mrow = m0 + 64 * wr + 16 * fm + 4 * lg;
#pragma unroll
    for (int fn = 0; fn < 4; ++fn) {
      const int ncol = n0 + 64 * wc + 16 * fn + lj;
      const float bn = BIAS_N ? bias[ncol] : 0.0f;
#pragma unroll
      for (int r = 0; r < 4; ++r) {
        float val = acc[fm][fn][r] + (BIAS_N ? bn : bias[mrow + r]);
        Cb[(size_t)(mrow + r) * cld + ncol] = val;
      }
    }
  }
}

// ---------------------------------------------------------------------------
// FUSED MFMA autocorrelation + candidate selection + f64 refinement + top-40.
// (Round-12 structure, PASSED at absmax floor — unchanged.)
// ---------------------------------------------------------------------------
template <int P>
__device__ __forceinline__ void ac_kloop(const char* __restrict__ qb,
                                         const char* __restrict__ kb,
                                         const int* __restrict__ aswz,
                                         int bbyte, f4 acc[4]) {
#pragma unroll
  for (int it = 0; it < 12; ++it) {
    const int t512 = it * 512;
    const int b512 = bbyte + t512;
    const int msk = ((b512 >> 9) & 7) << 4;
    const int e0 = b512 ^ msk;
    const int e1 = (b512 + 64) ^ msk;
#pragma unroll
    for (int u = 0; u < 8; ++u) {
      i4 w0 = *(const i4*)(qb + (aswz[2 * u] + t512));
      i4 w1 = *(const i4*)(qb + (aswz[2 * u + 1] + t512));
      uint_t w[8] = { (uint_t)w0.x, (uint_t)w0.y, (uint_t)w0.z, (uint_t)w0.w,
                      (uint_t)w1.x, (uint_t)w1.y, (uint_t)w1.z, (uint_t)w1.w };
      const int bb = ((u & 1) ? e1 : e0) + 128 * (u >> 1);
      bh8 Bf = *(const bh8*)(kb + bb);
#pragma unroll
      for (int e = 0; e < 4; ++e) {
        const int ro = (e >> 1) + 2 * P;
        const int sh = (e & 1) * 16;
        uint_t a0v = (uint_t)((((unsigned long long)w[ro + 1] << 32) | w[ro + 0]) >> sh);
        uint_t a1v = (uint_t)((((unsigned long long)w[ro + 2] << 32) | w[ro + 1]) >> sh);
        uint_t a2v = (uint_t)((((unsigned long long)w[ro + 3] << 32) | w[ro + 2]) >> sh);
        uint_t a3v = (uint_t)((((unsigned long long)w[ro + 4] << 32) | w[ro + 3]) >> sh);
        i4 ai = { (int)a0v, (int)a1v, (int)a2v, (int)a3v };
        bh8 Af = __builtin_bit_cast(bh8, ai);
        acc[e] = __builtin_amdgcn_mfma_f32_16x16x32_bf16(Af, Bf, acc[e], 0, 0, 0);
      }
    }
  }
}

__global__ __launch_bounds__(256) void cand_refine_kernel(const float* __restrict__ Q,
                                                          const float* __restrict__ K,
                                                          double* __restrict__ top_vals,
                                                          int* __restrict__ top_idx,
                                                          int c0) {
  // phase A: [0,6912) q bf16 (swz) | [6912,18688) k bf16 (swz)
  // post-kloop: ac f32 at [0,12288)
  // phase C:   qf f32 [0,12292) (incl. qf[L] pad) | kf f32 [12304,24592)
  __shared__ __align__(16) char smem[24608];
  __shared__ float redf[8];
  __shared__ int   redi[4];
  __shared__ int   cnt_s;
  __shared__ float cv[NCAND_];
  __shared__ int   ci[NCAND_];
  __shared__ float sv[TOPK_];
  __shared__ int   si[TOPK_];
  __shared__ double refv[RFN_];
  char* kbase = smem + 6912;
  float* ac_s = (float*)smem;
  const int c = blockIdx.x;
  const int tid = threadIdx.x;
  const float* Qp = Q + (size_t)c * L_;
  const float* Kp = K + (size_t)c * L_;

  // ---- Phase A staging: f32 -> bf16 (cvt_pk), swizzled stores ----
  for (int x8 = tid; x8 < 432; x8 += 256) {
    int x = x8 * 8; int src = x - (x >= L_ ? L_ : 0);
    float4 f0 = *(const float4*)(Qp + src);
    float4 f1 = *(const float4*)(Qp + src + 4);
    i4 pk = { (int)cvt_pk_bf16(f0.x, f0.y), (int)cvt_pk_bf16(f0.z, f0.w),
              (int)cvt_pk_bf16(f1.x, f1.y), (int)cvt_pk_bf16(f1.z, f1.w) };
    *(i4*)(smem + swzq(16 * x8)) = pk;
  }
  for (int x8 = tid; x8 < 736; x8 += 256) {
    int x = x8 * 8; int src = x - 2816 + (x < 2816 ? L_ : 0);
    float4 f0 = *(const float4*)(Kp + src);
    float4 f1 = *(const float4*)(Kp + src + 4);
    i4 pk = { (int)cvt_pk_bf16(f0.x, f0.y), (int)cvt_pk_bf16(f0.z, f0.w),
              (int)cvt_pk_bf16(f1.x, f1.y), (int)cvt_pk_bf16(f1.z, f1.w) };
    *(i4*)(kbase + swzk(16 * x8)) = pk;
  }
  __syncthreads();

  const int lane = tid & 63, fg = tid >> 6;
  const int lg = lane >> 4, lj = lane & 15;
  const int abyte = 16 * lg + 32 * lj + 16 * (fg >> 1);
  const int jvalid = (lj < 12) ? 1 : 0;
  const int bbyte = 5632 + 16 * lg - (jvalid ? 512 * lj : 0);

  int aswz[16];
#pragma unroll
  for (int u = 0; u < 8; ++u) {
    aswz[2 * u]     = swzq(abyte + 64 * u);
    aswz[2 * u + 1] = swzq(abyte + 64 * u + 16);
  }

  f4 acc[4];
#pragma unroll
  for (int e = 0; e < 4; ++e) acc[e] = (f4){0.f, 0.f, 0.f, 0.f};

  if (fg & 1) ac_kloop<1>(smem, kbase, aswz, bbyte, acc);
  else        ac_kloop<0>(smem, kbase, aswz, bbyte, acc);

  __syncthreads();   // all kloop q/k reads done before ac overlays them

  if (jvalid) {
#pragma unroll
    for (int e = 0; e < 4; ++e) {
      int f = 4 * fg + e;
#pragma unroll
      for (int r = 0; r < 4; ++r) {
        int g = f + 16 * (4 * lg + r);      // fine lag in [0,256)
        ac_s[lj + 12 * g] = acc[e][r];      // tau = g + 256*lj
      }
    }
  }
  __syncthreads();

  float v[12];
#pragma unroll
  for (int it = 0; it < 12; ++it) v[it] = ac_s[tid + 256 * it];

  // block max
  float lm = v[0];
#pragma unroll
  for (int it = 1; it < 12; ++it) lm = fmaxf(lm, v[it]);
  for (int o = 32; o; o >>= 1) lm = fmaxf(lm, __shfl_down(lm, o));
  if ((tid & 63) == 0) redf[tid >> 6] = lm;
  __syncthreads();
  if (tid == 0) redf[4] = fmaxf(fmaxf(redf[0], redf[1]), fmaxf(redf[2], redf[3]));
  __syncthreads();
  const float Tmax = redf[4];

  auto bcount = [&](float T) -> int {
    int lc = 0;
#pragma unroll
    for (int it = 0; it < 12; ++it) lc += (v[it] > T) ? 1 : 0;
    for (int o = 32; o; o >>= 1) lc += __shfl_down(lc, o);
    __syncthreads();
    if ((tid & 63) == 0) redi[tid >> 6] = lc;
    __syncthreads();
    return redi[0] + redi[1] + redi[2] + redi[3];
  };

  float lo = Tmax - 128.0f;
  int cl = bcount(lo);
  for (int wd = 1; wd <= 5 && cl < CFLOOR_; ++wd) {
    lo = Tmax - 128.0f * (float)(1 << wd); cl = bcount(lo);
  }
  float hi = Tmax, T = lo;
  int cT = cl;
  for (int i = 0; i < 26 && cT > NCAND_; ++i) {
    float mid = 0.5f * (lo + hi);
    int cm = bcount(mid);
    if (cm >= CFLOOR_) { lo = mid; T = mid; cT = cm; } else hi = mid;
  }

  if (tid == 0) cnt_s = 0;
  __syncthreads();
#pragma unroll
  for (int it = 0; it < 12; ++it) {
    if (v[it] > T) {
      int pos = atomicAdd(&cnt_s, 1);
      if (pos < NCAND_) {
        int m = tid + 256 * it;
        int g = m / 12, j = m - 12 * g;
        cv[pos] = v[it];
        ci[pos] = g + 256 * j;
      }
    }
  }
  __syncthreads();
  const int cnt = cnt_s < NCAND_ ? cnt_s : NCAND_;

  // ---- Phase B (wave 0: rank-based f32 top-40) || C-staging (waves 1-3) ---
  float* qf = (float*)smem;
  float* kf = (float*)(smem + 12304);
  if (tid >= 64) {
    for (int i = (tid - 64) * 4; i < L_; i += 768) {
      *(float4*)&qf[i] = *(const float4*)(Qp + i);
      *(float4*)&kf[i] = *(const float4*)(Kp + i);
    }
    if (tid == 64) qf[L_] = qf[0];   // circular pad for phase-C pair reads
  } else {
    float vi = (tid < cnt) ? cv[tid] : -1e30f;
    int   ii = (tid < cnt) ? ci[tid] : (1 << 30);
    int rank = 0;
#pragma unroll 8
    for (int j = 0; j < 64; ++j) {
      float vj = __shfl(vi, j);
      int   ij = __shfl(ii, j);
      rank += ((vj > vi) || (vj == vi && ij < ii)) ? 1 : 0;
    }
    if (rank < TOPK_) { sv[rank] = vi; si[rank] = (ii < L_) ? ii : 0; }
  }
  __syncthreads();

  // ---- Phase C: exact f64 ac for top-RFN_, one WAVE per candidate, 2-wide -
  for (int r = fg; r < RFN_; r += 4) {
    const int tau = si[r];
    double a = 0.0;
#pragma unroll 4
    for (int u = 0; u < 24; ++u) {
      int t = 2 * lane + 128 * u;
      int qi = t + tau; qi -= (qi >= L_) ? L_ : 0;
      float q0 = qf[qi], q1 = qf[qi + 1];
      float k0 = kf[t],  k1 = kf[t + 1];
      a = fma((double)q0, (double)k0, a);
      a = fma((double)q1, (double)k1, a);
    }
#pragma unroll
    for (int o = 32; o; o >>= 1) a += __shfl_down(a, o);
    if (lane == 0) refv[r] = a;
  }
  __syncthreads();

  // ---- Phase D: rank-based f64 sort of refined -> ranks 0..RFN_-1;
  //      ranks RFN_..39 from f32 order (rounds 3/4 proven harmless) ----
  double* out_v = top_vals + (size_t)(c0 + c) * TOPK_;
  int*    out_i = top_idx  + (size_t)(c0 + c) * TOPK_;
  if (tid < 64) {
    double dv = (tid < RFN_) ? refv[tid] : -1e300;
    int    di = (tid < RFN_) ? si[tid]   : (1 << 30);
    int rank = 0;
#pragma unroll 8
    for (int j = 0; j < RFN_; ++j) {
      double dj = __shfl(dv, j);
      int    ij = __shfl(di, j);
      rank += ((dj > dv) || (dj == dv && ij < di)) ? 1 : 0;
    }
    if (tid < RFN_) { out_v[rank] = dv; out_i[rank] = di; }
    if (tid >= RFN_ && tid < TOPK_) {
      out_v[tid] = (double)sv[tid];
      out_i[tid] = si[tid];
    }
  }
}

// ---------------------------------------------------------------------------
__global__ __launch_bounds__(256) void shifts_kernel(const int* __restrict__ top_idx,
                                                     int* __restrict__ shifts) {
  const int k = blockIdx.x;
  __shared__ double sred[256];
  double s = 0.0;
  for (int c = threadIdx.x; c < CH_; c += 256) s += (double)top_idx[(size_t)c * TOPK_ + k];
  sred[threadIdx.x] = s;
  __syncthreads();
  for (int o = 128; o > 0; o >>= 1) {
    if (threadIdx.x < o) sred[threadIdx.x] += sred[threadIdx.x + o];
    __syncthreads();
  }
  if (threadIdx.x == 0) shifts[k] = (int)((float)(sred[0] / (double)CH_));
}

__global__ __launch_bounds__(256) void softmax_kernel(const double* __restrict__ top_vals,
                                                      float* __restrict__ weights) {
  const int c = blockIdx.x * 256 + threadIdx.x;
  const double* v = top_vals + (size_t)c * TOPK_;
  double m = v[0];
  for (int k = 1; k < TOPK_; ++k) m = fmax(m, v[k]);
  double sum = 0.0;
  for (int k = 0; k < TOPK_; ++k) sum += exp(v[k] - m);
  double inv = 1.0 / sum;
  for (int k = 0; k < TOPK_; ++k)
    weights[(size_t)c * TOPK_ + k] = (float)(exp(v[k] - m) * inv);
}

// agg[c][t] = sum_k w[c][k] * V[c][(t+shift[k]) mod L], in place.
__global__ __launch_bounds__(256) void agg_kernel(float* __restrict__ Vc,
                                                  const float* __restrict__ weights,
                                                  const int* __restrict__ shifts) {
  const int c = blockIdx.x;
  __shared__ float v_s[L_ + 4];
  __shared__ float w_s[TOPK_];
  __shared__ int   s_s[TOPK_];
  float* row = Vc + (size_t)c * L_;
  for (int i = threadIdx.x * 4; i < L_; i += 1024)
    *(float4*)&v_s[i] = *(const float4*)(row + i);
  if (threadIdx.x < TOPK_) {
    w_s[threadIdx.x] = weights[(size_t)c * TOPK_ + threadIdx.x];
    s_s[threadIdx.x] = shifts[threadIdx.x];
  }
  __syncthreads();
  if (threadIdx.x < 4) v_s[L_ + threadIdx.x] = v_s[threadIdx.x];
  __syncthreads();
  for (int t = threadIdx.x * 4; t < L_; t += 1024) {
    float s0 = 0.f, s1 = 0.f, s2 = 0.f, s3 = 0.f;
#pragma unroll
    for (int k = 0; k < TOPK_; ++k) {
      int idx = t + s_s[k];
      if (idx >= L_) idx -= L_;
      const float w = w_s[k];
      s0 = fmaf(w, v_s[idx],     s0);
      s1 = fmaf(w, v_s[idx + 1], s1);
      s2 = fmaf(w, v_s[idx + 2], s2);
      s3 = fmaf(w, v_s[idx + 3], s3);
    }
    float4 o = { s0, s1, s2, s3 };
    *(float4*)(row + t) = o;
  }
}

// ---------------------------------------------------------------------------
extern "C" void kernel_launch(void* const* d_in, const int* in_sizes, int n_in,
                              void* d_out, int out_size, void* d_ws, size_t ws_size,
                              hipStream_t stream) {
  const float* query = (const float*)d_in[0];
  const float* key   = (const float*)d_in[1];
  const float* value = (const float*)d_in[2];
  const float* Wq = (const float*)d_in[3];
  const float* bq = (const float*)d_in[4];
  const float* Wk = (const float*)d_in[5];
  const float* bk = (const float*)d_in[6];
  const float* Wv = (const float*)d_in[7];
  const float* bvp = (const float*)d_in[8];
  const float* Wo = (const float*)d_in[9];
  const float* bo = (const float*)d_in[10];
  float* out = (float*)d_out;
  char* ws = (char*)d_ws;

  auto al = [](size_t x) { return (x + 255) & ~(size_t)255; };
  size_t off = 0;
  const size_t tv_off = off; off = al(off + (size_t)CH_ * TOPK_ * 8);
  const size_t ti_off = off; off = al(off + (size_t)CH_ * TOPK_ * 4);
  const size_t w_off  = off; off = al(off + (size_t)CH_ * TOPK_ * 4);
  const size_t sh_off = off; off = al(off + (size_t)TOPK_ * 4);
  const size_t small_end = off;                       // ~5.3 MB

  const size_t QK1   = (size_t)D_ * L_ * 4;           // 6.29 MB f32, one batch
  const size_t PBQK  = al(2 * QK1);                   // ~12.6 MB per batch
  const size_t AGG_BYTES    = (size_t)CH_ * L_ * 4;   // 96 MB
  const size_t BOUNCE_BYTES = (size_t)D_ * L_ * 4;    // 6 MB

  int nb; bool bounce;
  if (ws_size >= small_end + AGG_BYTES + PBQK) {
    bounce = false;
    size_t n = (ws_size - small_end - AGG_BYTES) / PBQK;
    nb = (int)(n > 16 ? 16 : n);
  } else {
    bounce = true;
    size_t rem = (ws_size > small_end + BOUNCE_BYTES) ? (ws_size - small_end - BOUNCE_BYTES) : 0;
    size_t n = rem / PBQK; nb = (int)(n > 16 ? 16 : n);
    if (nb < 1) nb = 1;
  }

  double* top_vals = (double*)(ws + tv_off);
  int*    top_idx  = (int*)(ws + ti_off);
  float*  weights  = (float*)(ws + w_off);
  int*    shifts   = (int*)(ws + sh_off);

  float* VcAgg;
  float* bounce_buf = nullptr;
  size_t qk_off;
  if (!bounce) {
    VcAgg = (float*)(ws + small_end);
    qk_off = small_end + al(AGG_BYTES);
  } else {
    bounce_buf = (float*)(ws + small_end);
    qk_off = small_end + al(BOUNCE_BYTES);
    VcAgg = (float*)d_out;
  }
  float* Qc = (float*)(ws + qk_off);
  float* Kc = (float*)(ws + qk_off + al((size_t)nb * QK1));

  dim3 blk(256);
  const long bXS = (long)L_ * D_;   // batch stride of inputs / out
  const long cQS = (long)D_ * L_;   // batch stride of channel-major tensors

  for (int b0 = 0; b0 < B_; b0 += nb) {
    int nbb = (B_ - b0 < nb) ? (B_ - b0) : nb;
    dim3 gp(L_ / 128, D_ / 128, nbb);   // (24, 4, nbb)
    gemm_mfma<6, false, false><<<gp, blk, 0, stream>>>(
        Wq, query + (size_t)b0 * L_ * D_, bq, Qc, 0, bXS, cQS, L_);
    gemm_mfma<6, false, false><<<gp, blk, 0, stream>>>(
        Wk, key + (size_t)b0 * L_ * D_, bk, Kc, 0, bXS, cQS, L_);
    cand_refine_kernel<<<nbb * D_, blk, 0, stream>>>(Qc, Kc, top_vals, top_idx, b0 * D_);
  }
  shifts_kernel<<<TOPK_, blk, 0, stream>>>(top_idx, shifts);
  softmax_kernel<<<CH_ / 256, blk, 0, stream>>>(top_vals, weights);

  {
    dim3 gp(L_ / 128, D_ / 128, B_);
    gemm_mfma<1, false, false><<<gp, blk, 0, stream>>>(
        Wv, value, bvp, VcAgg, 0, bXS, cQS, L_);
  }
  agg_kernel<<<CH_, blk, 0, stream>>>(VcAgg, weights, shifts);

  if (!bounce) {
    dim3 go(D_ / 128, L_ / 128, B_);    // (4, 24, 16)
    gemm_mfma<1, true, true><<<go, blk, 0, stream>>>(
        VcAgg, Wo, bo, out, cQS, 0, bXS, D_);
  } else {
    for (int b = 0; b < B_; ++b) {
      hipMemcpyAsync(bounce_buf, VcAgg + (size_t)b * D_ * L_, BOUNCE_BYTES,
                     hipMemcpyDeviceToDevice, stream);
      dim3 go(D_ / 128, L_ / 128, 1);
      gemm_mfma<1, true, true><<<go, blk, 0, stream>>>(
          bounce_buf, Wo, bo, out + (size_t)b * L_ * D_, 0, 0, 0, D_);
    }
  }
  (void)in_sizes; (void)n_in; (void)out_size;
}

// Round 16
// 1054.364 us; speedup vs baseline: 1.3407x; 1.0210x over previous
//
#include <hip/hip_runtime.h>
#include <hip/hip_bf16.h>
#include <math.h>

#define B_ 16
#define L_ 3072
#define D_ 512
#define CH_ (B_ * D_)   // 8192 channels
#define TOPK_ 40
#define NCAND_ 64       // candidate slots per channel
#define CFLOOR_ 52      // candidate count floor (>= RFN_ always)
#define RFN_ 24         // candidates refined exactly in f64 (rounds 3/4 proven)

typedef unsigned short ushort_t;
typedef unsigned int uint_t;
typedef __attribute__((ext_vector_type(8))) short bh8;   // 8 bf16 (4 VGPRs)
typedef __attribute__((ext_vector_type(4))) float f4;    // 4 f32 acc
typedef __attribute__((ext_vector_type(4))) int i4;      // 16B vector

__device__ __forceinline__ uint_t cvt_pk_bf16(float a, float b) {
  uint_t r;
  asm("v_cvt_pk_bf16_f32 %0, %1, %2" : "=v"(r) : "v"(a), "v"(b));
  return r;  // lo ushort = bf16(a), hi ushort = bf16(b)
}

// LDS byte-address swizzles (involutions; preserve 16B alignment)
__device__ __forceinline__ int swzq(int b) { return b ^ (((b >> 7) & 3) << 4); }
__device__ __forceinline__ int swzk(int b) { return b ^ (((b >> 9) & 7) << 4); }

// ---------------------------------------------------------------------------
// MFMA GEMM core, 128x128 tile, 4 waves. C[m][n] = sum_k A[m][k] B[n][k]+bias.
// NPASS=1: plain bf16 (V proj, out GEMM — round-4/8 PROVEN, absmax floor).
// NPASS=6: 3-way split-bf16 (h/m/l, Sterbenz-exact residuals; products
//   hh+hm+mh+mm+hl+lh) -> dP ~1.5e-6, round-15 PROVEN on HW (absmax floor).
// ---------------------------------------------------------------------------
template <int NPASS, int BK, int ST>
__device__ __forceinline__ void stage_rows(const float* __restrict__ g0,
                                           ushort_t* __restrict__ Hh,
                                           ushort_t* __restrict__ Hm,
                                           ushort_t* __restrict__ Hl,
                                           int tid) {
  const int row = tid >> 1;
  const int cb = (tid & 1) * (BK / 2);
  const float* g = g0 + (size_t)row * 512 + cb;
  ushort_t* ph = Hh + row * ST + cb;
  ushort_t* pm = Hm + row * ST + cb;
  ushort_t* pl = Hl + row * ST + cb;
#pragma unroll
  for (int p = 0; p < BK / 8; ++p) {
    float4 v = *(const float4*)(g + 4 * p);
    uint_t h01 = cvt_pk_bf16(v.x, v.y);
    uint_t h23 = cvt_pk_bf16(v.z, v.w);
    *(uint2*)(ph + 4 * p) = make_uint2(h01, h23);
    if (NPASS >= 3) {
      float x0 = __builtin_bit_cast(float, h01 << 16);
      float x1 = __builtin_bit_cast(float, h01 & 0xFFFF0000u);
      float x2 = __builtin_bit_cast(float, h23 << 16);
      float x3 = __builtin_bit_cast(float, h23 & 0xFFFF0000u);
      float r0 = v.x - x0, r1 = v.y - x1, r2 = v.z - x2, r3 = v.w - x3;
      uint_t m01 = cvt_pk_bf16(r0, r1);
      uint_t m23 = cvt_pk_bf16(r2, r3);
      if (NPASS == 3) {
        *(uint2*)(pl + 4 * p) = make_uint2(m01, m23);
      } else {  // NPASS == 6: store m, then exact third level l
        *(uint2*)(pm + 4 * p) = make_uint2(m01, m23);
        float y0 = __builtin_bit_cast(float, m01 << 16);
        float y1 = __builtin_bit_cast(float, m01 & 0xFFFF0000u);
        float y2 = __builtin_bit_cast(float, m23 << 16);
        float y3 = __builtin_bit_cast(float, m23 & 0xFFFF0000u);
        uint_t l01 = cvt_pk_bf16(r0 - y0, r1 - y1);
        uint_t l23 = cvt_pk_bf16(r2 - y2, r3 - y3);
        *(uint2*)(pl + 4 * p) = make_uint2(l01, l23);
      }
    }
  }
}

template <int NPASS, bool ATR, bool BIAS_N>
__device__ __forceinline__ void gemm_core(const float* __restrict__ Asrc,
                                          const float* __restrict__ Bsrc,
                                          const float* __restrict__ bias,
                                          float* __restrict__ Cb,
                                          int n0, int m0, int cld,
                                          ushort_t* Ah, ushort_t* Bh,
                                          ushort_t* Am, ushort_t* Bm,
                                          ushort_t* Al, ushort_t* Bl) {
  constexpr int BK = (NPASS == 1) ? 64 : 32;
  constexpr int ST = (NPASS == 1) ? 72 : 40;
  const int tid = threadIdx.x;
  const int lane = tid & 63, w = tid >> 6;
  const int wr = w >> 1, wc = w & 1;
  const int lj = lane & 15, lg = lane >> 4;

  f4 acc[4][4];
#pragma unroll
  for (int fm = 0; fm < 4; ++fm)
#pragma unroll
    for (int fn = 0; fn < 4; ++fn) acc[fm][fn] = (f4){0.f, 0.f, 0.f, 0.f};

  for (int kc = 0; kc < 512; kc += BK) {
    if (!ATR) {
      stage_rows<NPASS, BK, ST>(Asrc + (size_t)m0 * 512 + kc, Ah, Am, Al, tid);
    } else {
      constexpr int TPC = 256 / BK;
      constexpr int TC  = 128 / TPC;
      const int jl = tid / TPC, ts = tid % TPC;
      const float* g = Asrc + (size_t)(kc + jl) * L_ + m0 + ts * TC;
#pragma unroll
      for (int p = 0; p < TC / 4; ++p) {
        float4 v = *(const float4*)(g + 4 * p);
        uint_t h01 = cvt_pk_bf16(v.x, v.y);
        uint_t h23 = cvt_pk_bf16(v.z, v.w);
        int t = ts * TC + 4 * p;
        Ah[(t + 0) * ST + jl] = (ushort_t)(h01 & 0xFFFFu);
        Ah[(t + 1) * ST + jl] = (ushort_t)(h01 >> 16);
        Ah[(t + 2) * ST + jl] = (ushort_t)(h23 & 0xFFFFu);
        Ah[(t + 3) * ST + jl] = (ushort_t)(h23 >> 16);
      }
    }
    stage_rows<NPASS, BK, ST>(Bsrc + (size_t)n0 * 512 + kc, Bh, Bm, Bl, tid);
    __syncthreads();

#pragma unroll
    for (int ks = 0; ks < BK / 32; ++ks) {
      const int kk = ks * 32 + 8 * lg;
      bh8 af[4], bf[4];
#pragma unroll
      for (int f = 0; f < 4; ++f)
        af[f] = *(const bh8*)&Ah[(64 * wr + 16 * f + lj) * ST + kk];
#pragma unroll
      for (int f = 0; f < 4; ++f)
        bf[f] = *(const bh8*)&Bh[(64 * wc + 16 * f + lj) * ST + kk];
#pragma unroll
      for (int fm = 0; fm < 4; ++fm)
#pragma unroll
        for (int fn = 0; fn < 4; ++fn)
          acc[fm][fn] = __builtin_amdgcn_mfma_f32_16x16x32_bf16(af[fm], bf[fn],
                                                                acc[fm][fn], 0, 0, 0);
      if (NPASS >= 3) {
        bh8 bl_[4];
#pragma unroll
        for (int f = 0; f < 4; ++f)
          bl_[f] = *(const bh8*)&Bl[(64 * wc + 16 * f + lj) * ST + kk];
        bh8 al_[4];
#pragma unroll
        for (int f = 0; f < 4; ++f)
          al_[f] = *(const bh8*)&Al[(64 * wr + 16 * f + lj) * ST + kk];
        if (NPASS == 3) {
#pragma unroll
          for (int fm = 0; fm < 4; ++fm)
#pragma unroll
            for (int fn = 0; fn < 4; ++fn)
              acc[fm][fn] = __builtin_amdgcn_mfma_f32_16x16x32_bf16(af[fm], bl_[fn],
                                                                    acc[fm][fn], 0, 0, 0);
#pragma unroll
          for (int fm = 0; fm < 4; ++fm)
#pragma unroll
            for (int fn = 0; fn < 4; ++fn)
              acc[fm][fn] = __builtin_amdgcn_mfma_f32_16x16x32_bf16(al_[fm], bf[fn],
                                                                    acc[fm][fn], 0, 0, 0);
        } else {
          bh8 am_[4], bm_[4];
#pragma unroll
          for (int f = 0; f < 4; ++f)
            am_[f] = *(const bh8*)&Am[(64 * wr + 16 * f + lj) * ST + kk];
#pragma unroll
          for (int f = 0; f < 4; ++f)
            bm_[f] = *(const bh8*)&Bm[(64 * wc + 16 * f + lj) * ST + kk];
#pragma unroll
          for (int fm = 0; fm < 4; ++fm)
#pragma unroll
            for (int fn = 0; fn < 4; ++fn)
              acc[fm][fn] = __builtin_amdgcn_mfma_f32_16x16x32_bf16(af[fm], bm_[fn],
                                                                    acc[fm][fn], 0, 0, 0);
#pragma unroll
          for (int fm = 0; fm < 4; ++fm)
#pragma unroll
            for (int fn = 0; fn < 4; ++fn)
              acc[fm][fn] = __builtin_amdgcn_mfma_f32_16x16x32_bf16(am_[fm], bf[fn],
                                                                    acc[fm][fn], 0, 0, 0);
#pragma unroll
          for (int fm = 0; fm < 4; ++fm)
#pragma unroll
            for (int fn = 0; fn < 4; ++fn)
              acc[fm][fn] = __builtin_amdgcn_mfma_f32_16x16x32_bf16(am_[fm], bm_[fn],
                                                                    acc[fm][fn], 0, 0, 0);
#pragma unroll
          for (int fm = 0; fm < 4; ++fm)
#pragma unroll
            for (int fn = 0; fn < 4; ++fn)
              acc[fm][fn] = __builtin_amdgcn_mfma_f32_16x16x32_bf16(af[fm], bl_[fn],
                                                                    acc[fm][fn], 0, 0, 0);
#pragma unroll
          for (int fm = 0; fm < 4; ++fm)
#pragma unroll
            for (int fn = 0; fn < 4; ++fn)
              acc[fm][fn] = __builtin_amdgcn_mfma_f32_16x16x32_bf16(al_[fm], bf[fn],
                                                                    acc[fm][fn], 0, 0, 0);
        }
      }
    }
    __syncthreads();
  }

#pragma unroll
  for (int fm = 0; fm < 4; ++fm) {
    const int mrow = m0 + 64 * wr + 16 * fm + 4 * lg;
#pragma unroll
    for (int fn = 0; fn < 4; ++fn) {
      const int ncol = n0 + 64 * wc + 16 * fn + lj;
      const float bn = BIAS_N ? bias[ncol] : 0.0f;
#pragma unroll
      for (int r = 0; r < 4; ++r) {
        float val = acc[fm][fn][r] + (BIAS_N ? bn : bias[mrow + r]);
        Cb[(size_t)(mrow + r) * cld + ncol] = val;
      }
    }
  }
}

// generic kernel (V proj NPASS1, out GEMM NPASS1-ATR)
template <int NPASS, bool ATR, bool BIAS_N>
__global__ __launch_bounds__(256) void gemm_mfma(const float* __restrict__ Ap,
                                                 const float* __restrict__ Bp,
                                                 const float* __restrict__ bias,
                                                 float* __restrict__ Cp,
                                                 long aBS, long bBS, long cBS,
                                                 int cld) {
  constexpr int ST = (NPASS == 1) ? 72 : 40;
  __shared__ ushort_t Ah[128 * ST];
  __shared__ ushort_t Bh[128 * ST];
  __shared__ ushort_t Al[(NPASS >= 3) ? 128 * ST : 8];
  __shared__ ushort_t Bl[(NPASS >= 3) ? 128 * ST : 8];
  __shared__ ushort_t Am[(NPASS == 6) ? 128 * ST : 8];
  __shared__ ushort_t Bm[(NPASS == 6) ? 128 * ST : 8];
  gemm_core<NPASS, ATR, BIAS_N>(Ap + (size_t)blockIdx.z * aBS,
                                Bp + (size_t)blockIdx.z * bBS, bias,
                                Cp + (size_t)blockIdx.z * cBS,
                                blockIdx.x * 128, blockIdx.y * 128, cld,
                                Ah, Bh, Am, Bm, Al, Bl);
}

// merged Q+K NPASS=6 projection (z-split); per-element math identical to the
// round-15 passing gemm_mfma<6> -> Qc/Kc bit-identical.
__global__ __launch_bounds__(256) void gemm6_qk(const float* __restrict__ Xq,
                                                const float* __restrict__ Xk,
                                                const float* __restrict__ Wq_,
                                                const float* __restrict__ Wk_,
                                                const float* __restrict__ bq_,
                                                const float* __restrict__ bk_,
                                                float* __restrict__ Pq,
                                                float* __restrict__ Pk,
                                                int nbb) {
  __shared__ ushort_t Ah[128 * 40];
  __shared__ ushort_t Bh[128 * 40];
  __shared__ ushort_t Al[128 * 40];
  __shared__ ushort_t Bl[128 * 40];
  __shared__ ushort_t Am[128 * 40];
  __shared__ ushort_t Bm[128 * 40];
  const int z = blockIdx.z;
  const bool isK = (z >= nbb);
  const int b = isK ? (z - nbb) : z;
  const float* Asrc = isK ? Wk_ : Wq_;
  const float* Bsrc = (isK ? Xk : Xq) + (size_t)b * L_ * D_;
  const float* bias = isK ? bk_ : bq_;
  float* Cb = (isK ? Pk : Pq) + (size_t)b * D_ * L_;
  gemm_core<6, false, false>(Asrc, Bsrc, bias, Cb,
                             blockIdx.x * 128, blockIdx.y * 128, L_,
                             Ah, Bh, Am, Bm, Al, Bl);
}

// ---------------------------------------------------------------------------
// FUSED MFMA autocorrelation + candidate selection + f64 refinement + top-40.
// Round-16 kloop: each wave reuses its A-window for 8 f-values (f = 8*fh + e,
// e<8; ro = e>>1 <= 3 -> max dword w[7], still just 2x b128) and waves split
// the t-range (th = fg>>1). LDS reads per MFMA HALVED vs round 15. The two
// t-half partial sums combine via deterministic write-then-add (f32
// re-association ~1 ulp << bf16 noise 0.09; top-24 f64-refined; deep-rank
// f32-order perturbations are the round-12-proven-harmless class).
// ---------------------------------------------------------------------------
__device__ __forceinline__ void ac_kloop8(const char* __restrict__ qb,
                                          const char* __restrict__ kb,
                                          const int* __restrict__ aswz,
                                          int bbyte, int tbase, f4 acc[8]) {
#pragma unroll
  for (int it = 0; it < 6; ++it) {
    const int t512 = tbase + it * 512;
    const int b512 = bbyte + t512;
    const int msk = ((b512 >> 9) & 7) << 4;
    const int e0 = b512 ^ msk;
    const int e1 = (b512 + 64) ^ msk;
#pragma unroll
    for (int u = 0; u < 8; ++u) {
      i4 w0 = *(const i4*)(qb + (aswz[2 * u] + t512));
      i4 w1 = *(const i4*)(qb + (aswz[2 * u + 1] + t512));
      uint_t w[8] = { (uint_t)w0.x, (uint_t)w0.y, (uint_t)w0.z, (uint_t)w0.w,
                      (uint_t)w1.x, (uint_t)w1.y, (uint_t)w1.z, (uint_t)w1.w };
      const int bb = ((u & 1) ? e1 : e0) + 128 * (u >> 1);
      bh8 Bf = *(const bh8*)(kb + bb);
#pragma unroll
      for (int e = 0; e < 8; ++e) {
        const int ro = e >> 1;
        const int sh = (e & 1) * 16;
        uint_t a0v = (uint_t)((((unsigned long long)w[ro + 1] << 32) | w[ro + 0]) >> sh);
        uint_t a1v = (uint_t)((((unsigned long long)w[ro + 2] << 32) | w[ro + 1]) >> sh);
        uint_t a2v = (uint_t)((((unsigned long long)w[ro + 3] << 32) | w[ro + 2]) >> sh);
        uint_t a3v = (uint_t)((((unsigned long long)w[ro + 4] << 32) | w[ro + 3]) >> sh);
        i4 ai = { (int)a0v, (int)a1v, (int)a2v, (int)a3v };
        bh8 Af = __builtin_bit_cast(bh8, ai);
        acc[e] = __builtin_amdgcn_mfma_f32_16x16x32_bf16(Af, Bf, acc[e], 0, 0, 0);
      }
    }
  }
}

__global__ __launch_bounds__(256) void cand_refine_kernel(const float* __restrict__ Q,
                                                          const float* __restrict__ K,
                                                          double* __restrict__ top_vals,
                                                          int* __restrict__ top_idx,
                                                          int c0) {
  // phase A: [0,6912) q bf16 (swz) | [6912,18688) k bf16 (swz)
  // post-kloop: ac f32 at [0,12288)
  // phase C:   qf f32 [0,12292) (incl. qf[L] pad) | kf f32 [12304,24592)
  __shared__ __align__(16) char smem[24608];
  __shared__ float redf[8];
  __shared__ int   redi[4];
  __shared__ int   cnt_s;
  __shared__ float cv[NCAND_];
  __shared__ int   ci[NCAND_];
  __shared__ float sv[TOPK_];
  __shared__ int   si[TOPK_];
  __shared__ double refv[RFN_];
  char* kbase = smem + 6912;
  float* ac_s = (float*)smem;
  const int c = blockIdx.x;
  const int tid = threadIdx.x;
  const float* Qp = Q + (size_t)c * L_;
  const float* Kp = K + (size_t)c * L_;

  // ---- Phase A staging: f32 -> bf16 (cvt_pk), swizzled stores ----
  for (int x8 = tid; x8 < 432; x8 += 256) {
    int x = x8 * 8; int src = x - (x >= L_ ? L_ : 0);
    float4 f0 = *(const float4*)(Qp + src);
    float4 f1 = *(const float4*)(Qp + src + 4);
    i4 pk = { (int)cvt_pk_bf16(f0.x, f0.y), (int)cvt_pk_bf16(f0.z, f0.w),
              (int)cvt_pk_bf16(f1.x, f1.y), (int)cvt_pk_bf16(f1.z, f1.w) };
    *(i4*)(smem + swzq(16 * x8)) = pk;
  }
  for (int x8 = tid; x8 < 736; x8 += 256) {
    int x = x8 * 8; int src = x - 2816 + (x < 2816 ? L_ : 0);
    float4 f0 = *(const float4*)(Kp + src);
    float4 f1 = *(const float4*)(Kp + src + 4);
    i4 pk = { (int)cvt_pk_bf16(f0.x, f0.y), (int)cvt_pk_bf16(f0.z, f0.w),
              (int)cvt_pk_bf16(f1.x, f1.y), (int)cvt_pk_bf16(f1.z, f1.w) };
    *(i4*)(kbase + swzk(16 * x8)) = pk;
  }
  __syncthreads();

  const int lane = tid & 63, fg = tid >> 6;
  const int lg = lane >> 4, lj = lane & 15;
  const int fh = fg & 1;          // f half: f = 8*fh + e
  const int th = fg >> 1;         // t half: tbase = th*3072 bytes
  const int abyte = 16 * lg + 32 * lj + 16 * fh;
  const int jvalid = (lj < 12) ? 1 : 0;
  const int bbyte = 5632 + 16 * lg - (jvalid ? 512 * lj : 0);
  const int tbase = th * 3072;

  int aswz[16];
#pragma unroll
  for (int u = 0; u < 8; ++u) {
    aswz[2 * u]     = swzq(abyte + 64 * u);
    aswz[2 * u + 1] = swzq(abyte + 64 * u + 16);
  }

  f4 acc[8];
#pragma unroll
  for (int e = 0; e < 8; ++e) acc[e] = (f4){0.f, 0.f, 0.f, 0.f};

  ac_kloop8(smem, kbase, aswz, bbyte, tbase, acc);

  __syncthreads();   // all kloop q/k reads done before ac overlays them

  if (th == 0 && jvalid) {
#pragma unroll
    for (int e = 0; e < 8; ++e) {
      int f = 8 * fh + e;
#pragma unroll
      for (int r = 0; r < 4; ++r) {
        int g = f + 16 * (4 * lg + r);      // fine lag in [0,256)
        ac_s[lj + 12 * g] = acc[e][r];      // tau = g + 256*lj
      }
    }
  }
  __syncthreads();
  if (th == 1 && jvalid) {
#pragma unroll
    for (int e = 0; e < 8; ++e) {
      int f = 8 * fh + e;
#pragma unroll
      for (int r = 0; r < 4; ++r) {
        int g = f + 16 * (4 * lg + r);
        ac_s[lj + 12 * g] += acc[e][r];
      }
    }
  }
  __syncthreads();

  float v[12];
#pragma unroll
  for (int it = 0; it < 12; ++it) v[it] = ac_s[tid + 256 * it];

  // block max
  float lm = v[0];
#pragma unroll
  for (int it = 1; it < 12; ++it) lm = fmaxf(lm, v[it]);
  for (int o = 32; o; o >>= 1) lm = fmaxf(lm, __shfl_down(lm, o));
  if ((tid & 63) == 0) redf[tid >> 6] = lm;
  __syncthreads();
  if (tid == 0) redf[4] = fmaxf(fmaxf(redf[0], redf[1]), fmaxf(redf[2], redf[3]));
  __syncthreads();
  const float Tmax = redf[4];

  auto bcount = [&](float T) -> int {
    int lc = 0;
#pragma unroll
    for (int it = 0; it < 12; ++it) lc += (v[it] > T) ? 1 : 0;
    for (int o = 32; o; o >>= 1) lc += __shfl_down(lc, o);
    __syncthreads();
    if ((tid & 63) == 0) redi[tid >> 6] = lc;
    __syncthreads();
    return redi[0] + redi[1] + redi[2] + redi[3];
  };

  float lo = Tmax - 128.0f;
  int cl = bcount(lo);
  for (int wd = 1; wd <= 5 && cl < CFLOOR_; ++wd) {
    lo = Tmax - 128.0f * (float)(1 << wd); cl = bcount(lo);
  }
  float hi = Tmax, T = lo;
  int cT = cl;
  for (int i = 0; i < 26 && cT > NCAND_; ++i) {
    float mid = 0.5f * (lo + hi);
    int cm = bcount(mid);
    if (cm >= CFLOOR_) { lo = mid; T = mid; cT = cm; } else hi = mid;
  }

  if (tid == 0) cnt_s = 0;
  __syncthreads();
#pragma unroll
  for (int it = 0; it < 12; ++it) {
    if (v[it] > T) {
      int pos = atomicAdd(&cnt_s, 1);
      if (pos < NCAND_) {
        int m = tid + 256 * it;
        int g = m / 12, j = m - 12 * g;
        cv[pos] = v[it];
        ci[pos] = g + 256 * j;
      }
    }
  }
  __syncthreads();
  const int cnt = cnt_s < NCAND_ ? cnt_s : NCAND_;

  // ---- Phase B (wave 0: rank-based f32 top-40) || C-staging (waves 1-3) ---
  float* qf = (float*)smem;
  float* kf = (float*)(smem + 12304);
  if (tid >= 64) {
    for (int i = (tid - 64) * 4; i < L_; i += 768) {
      *(float4*)&qf[i] = *(const float4*)(Qp + i);
      *(float4*)&kf[i] = *(const float4*)(Kp + i);
    }
    if (tid == 64) qf[L_] = qf[0];   // circular pad for phase-C pair reads
  } else {
    float vi = (tid < cnt) ? cv[tid] : -1e30f;
    int   ii = (tid < cnt) ? ci[tid] : (1 << 30);
    int rank = 0;
#pragma unroll 8
    for (int j = 0; j < 64; ++j) {
      float vj = __shfl(vi, j);
      int   ij = __shfl(ii, j);
      rank += ((vj > vi) || (vj == vi && ij < ii)) ? 1 : 0;
    }
    if (rank < TOPK_) { sv[rank] = vi; si[rank] = (ii < L_) ? ii : 0; }
  }
  __syncthreads();

  // ---- Phase C: exact f64 ac for top-RFN_, one WAVE per candidate, 2-wide -
  for (int r = fg; r < RFN_; r += 4) {
    const int tau = si[r];
    double a = 0.0;
#pragma unroll 4
    for (int u = 0; u < 24; ++u) {
      int t = 2 * lane + 128 * u;
      int qi = t + tau; qi -= (qi >= L_) ? L_ : 0;
      float q0 = qf[qi], q1 = qf[qi + 1];
      float k0 = kf[t],  k1 = kf[t + 1];
      a = fma((double)q0, (double)k0, a);
      a = fma((double)q1, (double)k1, a);
    }
#pragma unroll
    for (int o = 32; o; o >>= 1) a += __shfl_down(a, o);
    if (lane == 0) refv[r] = a;
  }
  __syncthreads();

  // ---- Phase D: rank-based f64 sort of refined -> ranks 0..RFN_-1;
  //      ranks RFN_..39 from f32 order (rounds 3/4 proven harmless) ----
  double* out_v = top_vals + (size_t)(c0 + c) * TOPK_;
  int*    out_i = top_idx  + (size_t)(c0 + c) * TOPK_;
  if (tid < 64) {
    double dv = (tid < RFN_) ? refv[tid] : -1e300;
    int    di = (tid < RFN_) ? si[tid]   : (1 << 30);
    int rank = 0;
#pragma unroll 8
    for (int j = 0; j < RFN_; ++j) {
      double dj = __shfl(dv, j);
      int    ij = __shfl(di, j);
      rank += ((dj > dv) || (dj == dv && ij < di)) ? 1 : 0;
    }
    if (tid < RFN_) { out_v[rank] = dv; out_i[rank] = di; }
    if (tid >= RFN_ && tid < TOPK_) {
      out_v[tid] = (double)sv[tid];
      out_i[tid] = si[tid];
    }
  }
}

// ---------------------------------------------------------------------------
__global__ __launch_bounds__(256) void shifts_kernel(const int* __restrict__ top_idx,
                                                     int* __restrict__ shifts) {
  const int k = blockIdx.x;
  __shared__ double sred[256];
  double s = 0.0;
  for (int c = threadIdx.x; c < CH_; c += 256) s += (double)top_idx[(size_t)c * TOPK_ + k];
  sred[threadIdx.x] = s;
  __syncthreads();
  for (int o = 128; o > 0; o >>= 1) {
    if (threadIdx.x < o) sred[threadIdx.x] += sred[threadIdx.x + o];
    __syncthreads();
  }
  if (threadIdx.x == 0) shifts[k] = (int)((float)(sred[0] / (double)CH_));
}

__global__ __launch_bounds__(256) void softmax_kernel(const double* __restrict__ top_vals,
                                                      float* __restrict__ weights) {
  const int c = blockIdx.x * 256 + threadIdx.x;
  const double* v = top_vals + (size_t)c * TOPK_;
  double m = v[0];
  for (int k = 1; k < TOPK_; ++k) m = fmax(m, v[k]);
  double sum = 0.0;
  for (int k = 0; k < TOPK_; ++k) sum += exp(v[k] - m);
  double inv = 1.0 / sum;
  for (int k = 0; k < TOPK_; ++k)
    weights[(size_t)c * TOPK_ + k] = (float)(exp(v[k] - m) * inv);
}

// agg[c][t] = sum_k w[c][k] * V[c][(t+shift[k]) mod L], in place.
__global__ __launch_bounds__(256) void agg_kernel(float* __restrict__ Vc,
                                                  const float* __restrict__ weights,
                                                  const int* __restrict__ shifts) {
  const int c = blockIdx.x;
  __shared__ float v_s[L_ + 4];
  __shared__ float w_s[TOPK_];
  __shared__ int   s_s[TOPK_];
  float* row = Vc + (size_t)c * L_;
  for (int i = threadIdx.x * 4; i < L_; i += 1024)
    *(float4*)&v_s[i] = *(const float4*)(row + i);
  if (threadIdx.x < TOPK_) {
    w_s[threadIdx.x] = weights[(size_t)c * TOPK_ + threadIdx.x];
    s_s[threadIdx.x] = shifts[threadIdx.x];
  }
  __syncthreads();
  if (threadIdx.x < 4) v_s[L_ + threadIdx.x] = v_s[threadIdx.x];
  __syncthreads();
  for (int t = threadIdx.x * 4; t < L_; t += 1024) {
    float s0 = 0.f, s1 = 0.f, s2 = 0.f, s3 = 0.f;
#pragma unroll
    for (int k = 0; k < TOPK_; ++k) {
      int idx = t + s_s[k];
      if (idx >= L_) idx -= L_;
      const float w = w_s[k];
      s0 = fmaf(w, v_s[idx],     s0);
      s1 = fmaf(w, v_s[idx + 1], s1);
      s2 = fmaf(w, v_s[idx + 2], s2);
      s3 = fmaf(w, v_s[idx + 3], s3);
    }
    float4 o = { s0, s1, s2, s3 };
    *(float4*)(row + t) = o;
  }
}

// ---------------------------------------------------------------------------
extern "C" void kernel_launch(void* const* d_in, const int* in_sizes, int n_in,
                              void* d_out, int out_size, void* d_ws, size_t ws_size,
                              hipStream_t stream) {
  const float* query = (const float*)d_in[0];
  const float* key   = (const float*)d_in[1];
  const float* value = (const float*)d_in[2];
  const float* Wq = (const float*)d_in[3];
  const float* bq = (const float*)d_in[4];
  const float* Wk = (const float*)d_in[5];
  const float* bk = (const float*)d_in[6];
  const float* Wv = (const float*)d_in[7];
  const float* bvp = (const float*)d_in[8];
  const float* Wo = (const float*)d_in[9];
  const float* bo = (const float*)d_in[10];
  float* out = (float*)d_out;
  char* ws = (char*)d_ws;

  auto al = [](size_t x) { return (x + 255) & ~(size_t)255; };
  size_t off = 0;
  const size_t tv_off = off; off = al(off + (size_t)CH_ * TOPK_ * 8);
  const size_t ti_off = off; off = al(off + (size_t)CH_ * TOPK_ * 4);
  const size_t w_off  = off; off = al(off + (size_t)CH_ * TOPK_ * 4);
  const size_t sh_off = off; off = al(off + (size_t)TOPK_ * 4);
  const size_t small_end = off;                       // ~5.3 MB

  const size_t QK1   = (size_t)D_ * L_ * 4;           // 6.29 MB f32, one batch
  const size_t PBQK  = al(2 * QK1);                   // ~12.6 MB per batch
  const size_t AGG_BYTES    = (size_t)CH_ * L_ * 4;   // 96 MB
  const size_t BOUNCE_BYTES = (size_t)D_ * L_ * 4;    // 6 MB

  int nb; bool bounce;
  if (ws_size >= small_end + AGG_BYTES + PBQK) {
    bounce = false;
    size_t n = (ws_size - small_end - AGG_BYTES) / PBQK;
    nb = (int)(n > 16 ? 16 : n);
  } else {
    bounce = true;
    size_t rem = (ws_size > small_end + BOUNCE_BYTES) ? (ws_size - small_end - BOUNCE_BYTES) : 0;
    size_t n = rem / PBQK; nb = (int)(n > 16 ? 16 : n);
    if (nb < 1) nb = 1;
  }

  double* top_vals = (double*)(ws + tv_off);
  int*    top_idx  = (int*)(ws + ti_off);
  float*  weights  = (float*)(ws + w_off);
  int*    shifts   = (int*)(ws + sh_off);

  float* VcAgg;
  float* bounce_buf = nullptr;
  size_t qk_off;
  if (!bounce) {
    VcAgg = (float*)(ws + small_end);
    qk_off = small_end + al(AGG_BYTES);
  } else {
    bounce_buf = (float*)(ws + small_end);
    qk_off = small_end + al(BOUNCE_BYTES);
    VcAgg = (float*)d_out;
  }
  float* Qc = (float*)(ws + qk_off);
  float* Kc = (float*)(ws + qk_off + al((size_t)nb * QK1));

  dim3 blk(256);
  const long bXS = (long)L_ * D_;   // batch stride of inputs / out
  const long cQS = (long)D_ * L_;   // batch stride of channel-major tensors

  for (int b0 = 0; b0 < B_; b0 += nb) {
    int nbb = (B_ - b0 < nb) ? (B_ - b0) : nb;
    dim3 gp(L_ / 128, D_ / 128, 2 * nbb);   // (24, 4, 2*nbb)
    gemm6_qk<<<gp, blk, 0, stream>>>(query + (size_t)b0 * L_ * D_,
                                     key   + (size_t)b0 * L_ * D_,
                                     Wq, Wk, bq, bk, Qc, Kc, nbb);
    cand_refine_kernel<<<nbb * D_, blk, 0, stream>>>(Qc, Kc, top_vals, top_idx, b0 * D_);
  }
  shifts_kernel<<<TOPK_, blk, 0, stream>>>(top_idx, shifts);
  softmax_kernel<<<CH_ / 256, blk, 0, stream>>>(top_vals, weights);

  {
    dim3 gp(L_ / 128, D_ / 128, B_);
    gemm_mfma<1, false, false><<<gp, blk, 0, stream>>>(
        Wv, value, bvp, VcAgg, 0, bXS, cQS, L_);
  }
  agg_kernel<<<CH_, blk, 0, stream>>>(VcAgg, weights, shifts);

  if (!bounce) {
    dim3 go(D_ / 128, L_ / 128, B_);    // (4, 24, 16)
    gemm_mfma<1, true, true><<<go, blk, 0, stream>>>(
        VcAgg, Wo, bo, out, cQS, 0, bXS, D_);
  } else {
    for (int b = 0; b < B_; ++b) {
      hipMemcpyAsync(bounce_buf, VcAgg + (size_t)b * D_ * L_, BOUNCE_BYTES,
                     hipMemcpyDeviceToDevice, stream);
      dim3 go(D_ / 128, L_ / 128, 1);
      gemm_mfma<1, true, true><<<go, blk, 0, stream>>>(
          bounce_buf, Wo, bo, out + (size_t)b * L_ * D_, 0, 0, 0, D_);
    }
  }
  (void)in_sizes; (void)n_in; (void)out_size;
}

// Round 17
// 1052.458 us; speedup vs baseline: 1.3431x; 1.0018x over previous
//
#include <hip/hip_runtime.h>
#include <hip/hip_bf16.h>
#include <math.h>

#define B_ 16
#define L_ 3072
#define D_ 512
#define CH_ (B_ * D_)   // 8192 channels
#define TOPK_ 40
#define NCAND_ 64       // candidate slots per channel
#define CFLOOR_ 52      // candidate count floor (>= RFN_ always)
#define RFN_ 24         // candidates refined exactly in f64 (rounds 3/4 proven)

typedef unsigned short ushort_t;
typedef unsigned int uint_t;
typedef __attribute__((ext_vector_type(8))) short bh8;   // 8 bf16 (4 VGPRs)
typedef __attribute__((ext_vector_type(4))) float f4;    // 4 f32 acc
typedef __attribute__((ext_vector_type(4))) int i4;      // 16B vector

__device__ __forceinline__ uint_t cvt_pk_bf16(float a, float b) {
  uint_t r;
  asm("v_cvt_pk_bf16_f32 %0, %1, %2" : "=v"(r) : "v"(a), "v"(b));
  return r;  // lo ushort = bf16(a), hi ushort = bf16(b)
}

// LDS byte-address swizzles (involutions; preserve 16B alignment)
__device__ __forceinline__ int swzq(int b) { return b ^ (((b >> 7) & 3) << 4); }
__device__ __forceinline__ int swzk(int b) { return b ^ (((b >> 9) & 7) << 4); }

// ---------------------------------------------------------------------------
// MFMA GEMM core, 128x128 tile, 4 waves. C[m][n] = sum_k A[m][k] B[n][k]+bias.
// NPASS=1: plain bf16 (V proj, out GEMM — round-4/8 PROVEN, absmax floor).
// NPASS=6: 3-way split-bf16 (h/m/l, Sterbenz-exact residuals; products
//   hh+hm+mh+mm+hl+lh) -> dP ~1.5e-6, round-15 PROVEN on HW (absmax floor).
// ---------------------------------------------------------------------------
template <int NPASS, int BK, int ST>
__device__ __forceinline__ void stage_rows(const float* __restrict__ g0,
                                           ushort_t* __restrict__ Hh,
                                           ushort_t* __restrict__ Hm,
                                           ushort_t* __restrict__ Hl,
                                           int tid) {
  const int row = tid >> 1;
  const int cb = (tid & 1) * (BK / 2);
  const float* g = g0 + (size_t)row * 512 + cb;
  ushort_t* ph = Hh + row * ST + cb;
  ushort_t* pm = Hm + row * ST + cb;
  ushort_t* pl = Hl + row * ST + cb;
#pragma unroll
  for (int p = 0; p < BK / 8; ++p) {
    float4 v = *(const float4*)(g + 4 * p);
    uint_t h01 = cvt_pk_bf16(v.x, v.y);
    uint_t h23 = cvt_pk_bf16(v.z, v.w);
    *(uint2*)(ph + 4 * p) = make_uint2(h01, h23);
    if (NPASS >= 3) {
      float x0 = __builtin_bit_cast(float, h01 << 16);
      float x1 = __builtin_bit_cast(float, h01 & 0xFFFF0000u);
      float x2 = __builtin_bit_cast(float, h23 << 16);
      float x3 = __builtin_bit_cast(float, h23 & 0xFFFF0000u);
      float r0 = v.x - x0, r1 = v.y - x1, r2 = v.z - x2, r3 = v.w - x3;
      uint_t m01 = cvt_pk_bf16(r0, r1);
      uint_t m23 = cvt_pk_bf16(r2, r3);
      if (NPASS == 3) {
        *(uint2*)(pl + 4 * p) = make_uint2(m01, m23);
      } else {  // NPASS == 6: store m, then exact third level l
        *(uint2*)(pm + 4 * p) = make_uint2(m01, m23);
        float y0 = __builtin_bit_cast(float, m01 << 16);
        float y1 = __builtin_bit_cast(float, m01 & 0xFFFF0000u);
        float y2 = __builtin_bit_cast(float, m23 << 16);
        float y3 = __builtin_bit_cast(float, m23 & 0xFFFF0000u);
        uint_t l01 = cvt_pk_bf16(r0 - y0, r1 - y1);
        uint_t l23 = cvt_pk_bf16(r2 - y2, r3 - y3);
        *(uint2*)(pl + 4 * p) = make_uint2(l01, l23);
      }
    }
  }
}

template <int NPASS, bool ATR, bool BIAS_N>
__device__ __forceinline__ void gemm_core(const float* __restrict__ Asrc,
                                          const float* __restrict__ Bsrc,
                                          const float* __restrict__ bias,
                                          float* __restrict__ Cb,
                                          int n0, int m0, int cld,
                                          ushort_t* Ah, ushort_t* Bh,
                                          ushort_t* Am, ushort_t* Bm,
                                          ushort_t* Al, ushort_t* Bl) {
  constexpr int BK = (NPASS == 1) ? 64 : 32;
  constexpr int ST = (NPASS == 1) ? 72 : 40;
  const int tid = threadIdx.x;
  const int lane = tid & 63, w = tid >> 6;
  const int wr = w >> 1, wc = w & 1;
  const int lj = lane & 15, lg = lane >> 4;

  f4 acc[4][4];
#pragma unroll
  for (int fm = 0; fm < 4; ++fm)
#pragma unroll
    for (int fn = 0; fn < 4; ++fn) acc[fm][fn] = (f4){0.f, 0.f, 0.f, 0.f};

  for (int kc = 0; kc < 512; kc += BK) {
    if (!ATR) {
      stage_rows<NPASS, BK, ST>(Asrc + (size_t)m0 * 512 + kc, Ah, Am, Al, tid);
    } else {
      constexpr int TPC = 256 / BK;
      constexpr int TC  = 128 / TPC;
      const int jl = tid / TPC, ts = tid % TPC;
      const float* g = Asrc + (size_t)(kc + jl) * L_ + m0 + ts * TC;
#pragma unroll
      for (int p = 0; p < TC / 4; ++p) {
        float4 v = *(const float4*)(g + 4 * p);
        uint_t h01 = cvt_pk_bf16(v.x, v.y);
        uint_t h23 = cvt_pk_bf16(v.z, v.w);
        int t = ts * TC + 4 * p;
        Ah[(t + 0) * ST + jl] = (ushort_t)(h01 & 0xFFFFu);
        Ah[(t + 1) * ST + jl] = (ushort_t)(h01 >> 16);
        Ah[(t + 2) * ST + jl] = (ushort_t)(h23 & 0xFFFFu);
        Ah[(t + 3) * ST + jl] = (ushort_t)(h23 >> 16);
      }
    }
    stage_rows<NPASS, BK, ST>(Bsrc + (size_t)n0 * 512 + kc, Bh, Bm, Bl, tid);
    __syncthreads();

#pragma unroll
    for (int ks = 0; ks < BK / 32; ++ks) {
      const int kk = ks * 32 + 8 * lg;
      bh8 af[4], bf[4];
#pragma unroll
      for (int f = 0; f < 4; ++f)
        af[f] = *(const bh8*)&Ah[(64 * wr + 16 * f + lj) * ST + kk];
#pragma unroll
      for (int f = 0; f < 4; ++f)
        bf[f] = *(const bh8*)&Bh[(64 * wc + 16 * f + lj) * ST + kk];
#pragma unroll
      for (int fm = 0; fm < 4; ++fm)
#pragma unroll
        for (int fn = 0; fn < 4; ++fn)
          acc[fm][fn] = __builtin_amdgcn_mfma_f32_16x16x32_bf16(af[fm], bf[fn],
                                                                acc[fm][fn], 0, 0, 0);
      if (NPASS >= 3) {
        bh8 bl_[4];
#pragma unroll
        for (int f = 0; f < 4; ++f)
          bl_[f] = *(const bh8*)&Bl[(64 * wc + 16 * f + lj) * ST + kk];
        bh8 al_[4];
#pragma unroll
        for (int f = 0; f < 4; ++f)
          al_[f] = *(const bh8*)&Al[(64 * wr + 16 * f + lj) * ST + kk];
        if (NPASS == 3) {
#pragma unroll
          for (int fm = 0; fm < 4; ++fm)
#pragma unroll
            for (int fn = 0; fn < 4; ++fn)
              acc[fm][fn] = __builtin_amdgcn_mfma_f32_16x16x32_bf16(af[fm], bl_[fn],
                                                                    acc[fm][fn], 0, 0, 0);
#pragma unroll
          for (int fm = 0; fm < 4; ++fm)
#pragma unroll
            for (int fn = 0; fn < 4; ++fn)
              acc[fm][fn] = __builtin_amdgcn_mfma_f32_16x16x32_bf16(al_[fm], bf[fn],
                                                                    acc[fm][fn], 0, 0, 0);
        } else {
          bh8 am_[4], bm_[4];
#pragma unroll
          for (int f = 0; f < 4; ++f)
            am_[f] = *(const bh8*)&Am[(64 * wr + 16 * f + lj) * ST + kk];
#pragma unroll
          for (int f = 0; f < 4; ++f)
            bm_[f] = *(const bh8*)&Bm[(64 * wc + 16 * f + lj) * ST + kk];
#pragma unroll
          for (int fm = 0; fm < 4; ++fm)
#pragma unroll
            for (int fn = 0; fn < 4; ++fn)
              acc[fm][fn] = __builtin_amdgcn_mfma_f32_16x16x32_bf16(af[fm], bm_[fn],
                                                                    acc[fm][fn], 0, 0, 0);
#pragma unroll
          for (int fm = 0; fm < 4; ++fm)
#pragma unroll
            for (int fn = 0; fn < 4; ++fn)
              acc[fm][fn] = __builtin_amdgcn_mfma_f32_16x16x32_bf16(am_[fm], bf[fn],
                                                                    acc[fm][fn], 0, 0, 0);
#pragma unroll
          for (int fm = 0; fm < 4; ++fm)
#pragma unroll
            for (int fn = 0; fn < 4; ++fn)
              acc[fm][fn] = __builtin_amdgcn_mfma_f32_16x16x32_bf16(am_[fm], bm_[fn],
                                                                    acc[fm][fn], 0, 0, 0);
#pragma unroll
          for (int fm = 0; fm < 4; ++fm)
#pragma unroll
            for (int fn = 0; fn < 4; ++fn)
              acc[fm][fn] = __builtin_amdgcn_mfma_f32_16x16x32_bf16(af[fm], bl_[fn],
                                                                    acc[fm][fn], 0, 0, 0);
#pragma unroll
          for (int fm = 0; fm < 4; ++fm)
#pragma unroll
            for (int fn = 0; fn < 4; ++fn)
              acc[fm][fn] = __builtin_amdgcn_mfma_f32_16x16x32_bf16(al_[fm], bf[fn],
                                                                    acc[fm][fn], 0, 0, 0);
        }
      }
    }
    __syncthreads();
  }

#pragma unroll
  for (int fm = 0; fm < 4; ++fm) {
    const int mrow = m0 + 64 * wr + 16 * fm + 4 * lg;
#pragma unroll
    for (int fn = 0; fn < 4; ++fn) {
      const int ncol = n0 + 64 * wc + 16 * fn + lj;
      const float bn = BIAS_N ? bias[ncol] : 0.0f;
#pragma unroll
      for (int r = 0; r < 4; ++r) {
        float val = acc[fm][fn][r] + (BIAS_N ? bn : bias[mrow + r]);
        Cb[(size_t)(mrow + r) * cld + ncol] = val;
      }
    }
  }
}

// generic kernel (V proj NPASS1, out GEMM NPASS1-ATR)
template <int NPASS, bool ATR, bool BIAS_N>
__global__ __launch_bounds__(256) void gemm_mfma(const float* __restrict__ Ap,
                                                 const float* __restrict__ Bp,
                                                 const float* __restrict__ bias,
                                                 float* __restrict__ Cp,
                                                 long aBS, long bBS, long cBS,
                                                 int cld) {
  constexpr int ST = (NPASS == 1) ? 72 : 40;
  __shared__ ushort_t Ah[128 * ST];
  __shared__ ushort_t Bh[128 * ST];
  __shared__ ushort_t Al[(NPASS >= 3) ? 128 * ST : 8];
  __shared__ ushort_t Bl[(NPASS >= 3) ? 128 * ST : 8];
  __shared__ ushort_t Am[(NPASS == 6) ? 128 * ST : 8];
  __shared__ ushort_t Bm[(NPASS == 6) ? 128 * ST : 8];
  gemm_core<NPASS, ATR, BIAS_N>(Ap + (size_t)blockIdx.z * aBS,
                                Bp + (size_t)blockIdx.z * bBS, bias,
                                Cp + (size_t)blockIdx.z * cBS,
                                blockIdx.x * 128, blockIdx.y * 128, cld,
                                Ah, Bh, Am, Bm, Al, Bl);
}

// merged Q+K NPASS=6 projection (z-split); per-element math identical to the
// round-15 passing gemm_mfma<6> -> Qc/Kc bit-identical.
__global__ __launch_bounds__(256) void gemm6_qk(const float* __restrict__ Xq,
                                                const float* __restrict__ Xk,
                                                const float* __restrict__ Wq_,
                                                const float* __restrict__ Wk_,
                                                const float* __restrict__ bq_,
                                                const float* __restrict__ bk_,
                                                float* __restrict__ Pq,
                                                float* __restrict__ Pk,
                                                int nbb) {
  __shared__ ushort_t Ah[128 * 40];
  __shared__ ushort_t Bh[128 * 40];
  __shared__ ushort_t Al[128 * 40];
  __shared__ ushort_t Bl[128 * 40];
  __shared__ ushort_t Am[128 * 40];
  __shared__ ushort_t Bm[128 * 40];
  const int z = blockIdx.z;
  const bool isK = (z >= nbb);
  const int b = isK ? (z - nbb) : z;
  const float* Asrc = isK ? Wk_ : Wq_;
  const float* Bsrc = (isK ? Xk : Xq) + (size_t)b * L_ * D_;
  const float* bias = isK ? bk_ : bq_;
  float* Cb = (isK ? Pk : Pq) + (size_t)b * D_ * L_;
  gemm_core<6, false, false>(Asrc, Bsrc, bias, Cb,
                             blockIdx.x * 128, blockIdx.y * 128, L_,
                             Ah, Bh, Am, Bm, Al, Bl);
}

// ---------------------------------------------------------------------------
// FUSED MFMA autocorrelation + candidate selection + f64 refinement + top-40.
// Round-17 (all bit-identical vs the round-16 pass):
//  - kloop: shared odd-e windows s[i] = funnel(w[i+1],w[i],16) computed ONCE
//    (7 ops feed 4 odd-e fragments; even-e fragments are direct w copies) —
//    same values, guaranteed CSE.
//  - dual ac buffers: th=1 waves write ac2 (no RMW, one barrier fewer);
//    v = ac1 + ac2 preserves the (th0 + th1) addition order.
//  - phase C: kf pair read as aligned float2 (t even); f64 chain unchanged.
// ---------------------------------------------------------------------------
__device__ __forceinline__ void ac_kloop8(const char* __restrict__ qb,
                                          const char* __restrict__ kb,
                                          const int* __restrict__ aswz,
                                          int bbyte, int tbase, f4 acc[8]) {
#pragma unroll
  for (int it = 0; it < 6; ++it) {
    const int t512 = tbase + it * 512;
    const int b512 = bbyte + t512;
    const int msk = ((b512 >> 9) & 7) << 4;
    const int e0 = b512 ^ msk;
    const int e1 = (b512 + 64) ^ msk;
#pragma unroll
    for (int u = 0; u < 8; ++u) {
      i4 w0 = *(const i4*)(qb + (aswz[2 * u] + t512));
      i4 w1 = *(const i4*)(qb + (aswz[2 * u + 1] + t512));
      uint_t w[8] = { (uint_t)w0.x, (uint_t)w0.y, (uint_t)w0.z, (uint_t)w0.w,
                      (uint_t)w1.x, (uint_t)w1.y, (uint_t)w1.z, (uint_t)w1.w };
      uint_t s[7];
#pragma unroll
      for (int i = 0; i < 7; ++i)
        s[i] = (uint_t)((((unsigned long long)w[i + 1] << 32) | w[i]) >> 16);
      const int bb = ((u & 1) ? e1 : e0) + 128 * (u >> 1);
      bh8 Bf = *(const bh8*)(kb + bb);
#pragma unroll
      for (int e = 0; e < 8; ++e) {
        const int ro = e >> 1;
        i4 ai;
        if ((e & 1) == 0)
          ai = (i4){ (int)w[ro], (int)w[ro + 1], (int)w[ro + 2], (int)w[ro + 3] };
        else
          ai = (i4){ (int)s[ro], (int)s[ro + 1], (int)s[ro + 2], (int)s[ro + 3] };
        bh8 Af = __builtin_bit_cast(bh8, ai);
        acc[e] = __builtin_amdgcn_mfma_f32_16x16x32_bf16(Af, Bf, acc[e], 0, 0, 0);
      }
    }
  }
}

__global__ __launch_bounds__(256) void cand_refine_kernel(const float* __restrict__ Q,
                                                          const float* __restrict__ K,
                                                          double* __restrict__ top_vals,
                                                          int* __restrict__ top_idx,
                                                          int c0) {
  // phase A: [0,6912) q bf16 (swz) | [6912,18688) k bf16 (swz)
  // post-kloop: ac1 f32 [0,12288) | ac2 f32 [12288,24576)
  // phase C:   qf f32 [0,12292) (incl. qf[L] pad) | kf f32 [12304,24592)
  __shared__ __align__(16) char smem[24608];
  __shared__ float redf[8];
  __shared__ int   redi[4];
  __shared__ int   cnt_s;
  __shared__ float cv[NCAND_];
  __shared__ int   ci[NCAND_];
  __shared__ float sv[TOPK_];
  __shared__ int   si[TOPK_];
  __shared__ double refv[RFN_];
  char* kbase = smem + 6912;
  float* ac1 = (float*)smem;
  float* ac2 = (float*)(smem + 12288);
  const int c = blockIdx.x;
  const int tid = threadIdx.x;
  const float* Qp = Q + (size_t)c * L_;
  const float* Kp = K + (size_t)c * L_;

  // ---- Phase A staging: f32 -> bf16 (cvt_pk), swizzled stores ----
  for (int x8 = tid; x8 < 432; x8 += 256) {
    int x = x8 * 8; int src = x - (x >= L_ ? L_ : 0);
    float4 f0 = *(const float4*)(Qp + src);
    float4 f1 = *(const float4*)(Qp + src + 4);
    i4 pk = { (int)cvt_pk_bf16(f0.x, f0.y), (int)cvt_pk_bf16(f0.z, f0.w),
              (int)cvt_pk_bf16(f1.x, f1.y), (int)cvt_pk_bf16(f1.z, f1.w) };
    *(i4*)(smem + swzq(16 * x8)) = pk;
  }
  for (int x8 = tid; x8 < 736; x8 += 256) {
    int x = x8 * 8; int src = x - 2816 + (x < 2816 ? L_ : 0);
    float4 f0 = *(const float4*)(Kp + src);
    float4 f1 = *(const float4*)(Kp + src + 4);
    i4 pk = { (int)cvt_pk_bf16(f0.x, f0.y), (int)cvt_pk_bf16(f0.z, f0.w),
              (int)cvt_pk_bf16(f1.x, f1.y), (int)cvt_pk_bf16(f1.z, f1.w) };
    *(i4*)(kbase + swzk(16 * x8)) = pk;
  }
  __syncthreads();

  const int lane = tid & 63, fg = tid >> 6;
  const int lg = lane >> 4, lj = lane & 15;
  const int fh = fg & 1;          // f half: f = 8*fh + e
  const int th = fg >> 1;         // t half: tbase = th*3072 bytes
  const int abyte = 16 * lg + 32 * lj + 16 * fh;
  const int jvalid = (lj < 12) ? 1 : 0;
  const int bbyte = 5632 + 16 * lg - (jvalid ? 512 * lj : 0);
  const int tbase = th * 3072;

  int aswz[16];
#pragma unroll
  for (int u = 0; u < 8; ++u) {
    aswz[2 * u]     = swzq(abyte + 64 * u);
    aswz[2 * u + 1] = swzq(abyte + 64 * u + 16);
  }

  f4 acc[8];
#pragma unroll
  for (int e = 0; e < 8; ++e) acc[e] = (f4){0.f, 0.f, 0.f, 0.f};

  ac_kloop8(smem, kbase, aswz, bbyte, tbase, acc);

  __syncthreads();   // all kloop q/k reads done before ac overlays them

  if (jvalid) {
    float* dst = th ? ac2 : ac1;
#pragma unroll
    for (int e = 0; e < 8; ++e) {
      int f = 8 * fh + e;
#pragma unroll
      for (int r = 0; r < 4; ++r) {
        int g = f + 16 * (4 * lg + r);      // fine lag in [0,256)
        dst[lj + 12 * g] = acc[e][r];       // tau = g + 256*lj
      }
    }
  }
  __syncthreads();

  float v[12];
#pragma unroll
  for (int it = 0; it < 12; ++it)
    v[it] = ac1[tid + 256 * it] + ac2[tid + 256 * it];  // (th0 + th1) order

  // block max
  float lm = v[0];
#pragma unroll
  for (int it = 1; it < 12; ++it) lm = fmaxf(lm, v[it]);
  for (int o = 32; o; o >>= 1) lm = fmaxf(lm, __shfl_down(lm, o));
  if ((tid & 63) == 0) redf[tid >> 6] = lm;
  __syncthreads();
  if (tid == 0) redf[4] = fmaxf(fmaxf(redf[0], redf[1]), fmaxf(redf[2], redf[3]));
  __syncthreads();
  const float Tmax = redf[4];

  auto bcount = [&](float T) -> int {
    int lc = 0;
#pragma unroll
    for (int it = 0; it < 12; ++it) lc += (v[it] > T) ? 1 : 0;
    for (int o = 32; o; o >>= 1) lc += __shfl_down(lc, o);
    __syncthreads();
    if ((tid & 63) == 0) redi[tid >> 6] = lc;
    __syncthreads();
    return redi[0] + redi[1] + redi[2] + redi[3];
  };

  float lo = Tmax - 128.0f;
  int cl = bcount(lo);
  for (int wd = 1; wd <= 5 && cl < CFLOOR_; ++wd) {
    lo = Tmax - 128.0f * (float)(1 << wd); cl = bcount(lo);
  }
  float hi = Tmax, T = lo;
  int cT = cl;
  for (int i = 0; i < 26 && cT > NCAND_; ++i) {
    float mid = 0.5f * (lo + hi);
    int cm = bcount(mid);
    if (cm >= CFLOOR_) { lo = mid; T = mid; cT = cm; } else hi = mid;
  }

  if (tid == 0) cnt_s = 0;
  __syncthreads();
#pragma unroll
  for (int it = 0; it < 12; ++it) {
    if (v[it] > T) {
      int pos = atomicAdd(&cnt_s, 1);
      if (pos < NCAND_) {
        int m = tid + 256 * it;
        int g = m / 12, j = m - 12 * g;
        cv[pos] = v[it];
        ci[pos] = g + 256 * j;
      }
    }
  }
  __syncthreads();
  const int cnt = cnt_s < NCAND_ ? cnt_s : NCAND_;

  // ---- Phase B (wave 0: rank-based f32 top-40) || C-staging (waves 1-3) ---
  float* qf = (float*)smem;
  float* kf = (float*)(smem + 12304);
  if (tid >= 64) {
    for (int i = (tid - 64) * 4; i < L_; i += 768) {
      *(float4*)&qf[i] = *(const float4*)(Qp + i);
      *(float4*)&kf[i] = *(const float4*)(Kp + i);
    }
    if (tid == 64) qf[L_] = qf[0];   // circular pad for phase-C pair reads
  } else {
    float vi = (tid < cnt) ? cv[tid] : -1e30f;
    int   ii = (tid < cnt) ? ci[tid] : (1 << 30);
    int rank = 0;
#pragma unroll 8
    for (int j = 0; j < 64; ++j) {
      float vj = __shfl(vi, j);
      int   ij = __shfl(ii, j);
      rank += ((vj > vi) || (vj == vi && ij < ii)) ? 1 : 0;
    }
    if (rank < TOPK_) { sv[rank] = vi; si[rank] = (ii < L_) ? ii : 0; }
  }
  __syncthreads();

  // ---- Phase C: exact f64 ac for top-RFN_, one WAVE per candidate, 2-wide -
  for (int r = fg; r < RFN_; r += 4) {
    const int tau = si[r];
    double a = 0.0;
#pragma unroll 4
    for (int u = 0; u < 24; ++u) {
      int t = 2 * lane + 128 * u;
      int qi = t + tau; qi -= (qi >= L_) ? L_ : 0;
      float q0 = qf[qi], q1 = qf[qi + 1];
      float2 kv = *(const float2*)&kf[t];   // t even -> 8B aligned
      a = fma((double)q0, (double)kv.x, a);
      a = fma((double)q1, (double)kv.y, a);
    }
#pragma unroll
    for (int o = 32; o; o >>= 1) a += __shfl_down(a, o);
    if (lane == 0) refv[r] = a;
  }
  __syncthreads();

  // ---- Phase D: rank-based f64 sort of refined -> ranks 0..RFN_-1;
  //      ranks RFN_..39 from f32 order (rounds 3/4 proven harmless) ----
  double* out_v = top_vals + (size_t)(c0 + c) * TOPK_;
  int*    out_i = top_idx  + (size_t)(c0 + c) * TOPK_;
  if (tid < 64) {
    double dv = (tid < RFN_) ? refv[tid] : -1e300;
    int    di = (tid < RFN_) ? si[tid]   : (1 << 30);
    int rank = 0;
#pragma unroll 8
    for (int j = 0; j < RFN_; ++j) {
      double dj = __shfl(dv, j);
      int    ij = __shfl(di, j);
      rank += ((dj > dv) || (dj == dv && ij < di)) ? 1 : 0;
    }
    if (tid < RFN_) { out_v[rank] = dv; out_i[rank] = di; }
    if (tid >= RFN_ && tid < TOPK_) {
      out_v[tid] = (double)sv[tid];
      out_i[tid] = si[tid];
    }
  }
}

// ---------------------------------------------------------------------------
__global__ __launch_bounds__(256) void shifts_kernel(const int* __restrict__ top_idx,
                                                     int* __restrict__ shifts) {
  const int k = blockIdx.x;
  __shared__ double sred[256];
  double s = 0.0;
  for (int c = threadIdx.x; c < CH_; c += 256) s += (double)top_idx[(size_t)c * TOPK_ + k];
  sred[threadIdx.x] = s;
  __syncthreads();
  for (int o = 128; o > 0; o >>= 1) {
    if (threadIdx.x < o) sred[threadIdx.x] += sred[threadIdx.x + o];
    __syncthreads();
  }
  if (threadIdx.x == 0) shifts[k] = (int)((float)(sred[0] / (double)CH_));
}

__global__ __launch_bounds__(256) void softmax_kernel(const double* __restrict__ top_vals,
                                                      float* __restrict__ weights) {
  const int c = blockIdx.x * 256 + threadIdx.x;
  const double* v = top_vals + (size_t)c * TOPK_;
  double m = v[0];
  for (int k = 1; k < TOPK_; ++k) m = fmax(m, v[k]);
  double sum = 0.0;
  for (int k = 0; k < TOPK_; ++k) sum += exp(v[k] - m);
  double inv = 1.0 / sum;
  for (int k = 0; k < TOPK_; ++k)
    weights[(size_t)c * TOPK_ + k] = (float)(exp(v[k] - m) * inv);
}

// agg[c][t] = sum_k w[c][k] * V[c][(t+shift[k]) mod L], in place.
__global__ __launch_bounds__(256) void agg_kernel(float* __restrict__ Vc,
                                                  const float* __restrict__ weights,
                                                  const int* __restrict__ shifts) {
  const int c = blockIdx.x;
  __shared__ float v_s[L_ + 4];
  __shared__ float w_s[TOPK_];
  __shared__ int   s_s[TOPK_];
  float* row = Vc + (size_t)c * L_;
  for (int i = threadIdx.x * 4; i < L_; i += 1024)
    *(float4*)&v_s[i] = *(const float4*)(row + i);
  if (threadIdx.x < TOPK_) {
    w_s[threadIdx.x] = weights[(size_t)c * TOPK_ + threadIdx.x];
    s_s[threadIdx.x] = shifts[threadIdx.x];
  }
  __syncthreads();
  if (threadIdx.x < 4) v_s[L_ + threadIdx.x] = v_s[threadIdx.x];
  __syncthreads();
  for (int t = threadIdx.x * 4; t < L_; t += 1024) {
    float s0 = 0.f, s1 = 0.f, s2 = 0.f, s3 = 0.f;
#pragma unroll
    for (int k = 0; k < TOPK_; ++k) {
      int idx = t + s_s[k];
      if (idx >= L_) idx -= L_;
      const float w = w_s[k];
      s0 = fmaf(w, v_s[idx],     s0);
      s1 = fmaf(w, v_s[idx + 1], s1);
      s2 = fmaf(w, v_s[idx + 2], s2);
      s3 = fmaf(w, v_s[idx + 3], s3);
    }
    float4 o = { s0, s1, s2, s3 };
    *(float4*)(row + t) = o;
  }
}

// ---------------------------------------------------------------------------
extern "C" void kernel_launch(void* const* d_in, const int* in_sizes, int n_in,
                              void* d_out, int out_size, void* d_ws, size_t ws_size,
                              hipStream_t stream) {
  const float* query = (const float*)d_in[0];
  const float* key   = (const float*)d_in[1];
  const float* value = (const float*)d_in[2];
  const float* Wq = (const float*)d_in[3];
  const float* bq = (const float*)d_in[4];
  const float* Wk = (const float*)d_in[5];
  const float* bk = (const float*)d_in[6];
  const float* Wv = (const float*)d_in[7];
  const float* bvp = (const float*)d_in[8];
  const float* Wo = (const float*)d_in[9];
  const float* bo = (const float*)d_in[10];
  float* out = (float*)d_out;
  char* ws = (char*)d_ws;

  auto al = [](size_t x) { return (x + 255) & ~(size_t)255; };
  size_t off = 0;
  const size_t tv_off = off; off = al(off + (size_t)CH_ * TOPK_ * 8);
  const size_t ti_off = off; off = al(off + (size_t)CH_ * TOPK_ * 4);
  const size_t w_off  = off; off = al(off + (size_t)CH_ * TOPK_ * 4);
  const size_t sh_off = off; off = al(off + (size_t)TOPK_ * 4);
  const size_t small_end = off;                       // ~5.3 MB

  const size_t QK1   = (size_t)D_ * L_ * 4;           // 6.29 MB f32, one batch
  const size_t PBQK  = al(2 * QK1);                   // ~12.6 MB per batch
  const size_t AGG_BYTES    = (size_t)CH_ * L_ * 4;   // 96 MB
  const size_t BOUNCE_BYTES = (size_t)D_ * L_ * 4;    // 6 MB

  int nb; bool bounce;
  if (ws_size >= small_end + AGG_BYTES + PBQK) {
    bounce = false;
    size_t n = (ws_size - small_end - AGG_BYTES) / PBQK;
    nb = (int)(n > 16 ? 16 : n);
  } else {
    bounce = true;
    size_t rem = (ws_size > small_end + BOUNCE_BYTES) ? (ws_size - small_end - BOUNCE_BYTES) : 0;
    size_t n = rem / PBQK; nb = (int)(n > 16 ? 16 : n);
    if (nb < 1) nb = 1;
  }

  double* top_vals = (double*)(ws + tv_off);
  int*    top_idx  = (int*)(ws + ti_off);
  float*  weights  = (float*)(ws + w_off);
  int*    shifts   = (int*)(ws + sh_off);

  float* VcAgg;
  float* bounce_buf = nullptr;
  size_t qk_off;
  if (!bounce) {
    VcAgg = (float*)(ws + small_end);
    qk_off = small_end + al(AGG_BYTES);
  } else {
    bounce_buf = (float*)(ws + small_end);
    qk_off = small_end + al(BOUNCE_BYTES);
    VcAgg = (float*)d_out;
  }
  float* Qc = (float*)(ws + qk_off);
  float* Kc = (float*)(ws + qk_off + al((size_t)nb * QK1));

  dim3 blk(256);
  const long bXS = (long)L_ * D_;   // batch stride of inputs / out
  const long cQS = (long)D_ * L_;   // batch stride of channel-major tensors

  for (int b0 = 0; b0 < B_; b0 += nb) {
    int nbb = (B_ - b0 < nb) ? (B_ - b0) : nb;
    dim3 gp(L_ / 128, D_ / 128, 2 * nbb);   // (24, 4, 2*nbb)
    gemm6_qk<<<gp, blk, 0, stream>>>(query + (size_t)b0 * L_ * D_,
                                     key   + (size_t)b0 * L_ * D_,
                                     Wq, Wk, bq, bk, Qc, Kc, nbb);
    cand_refine_kernel<<<nbb * D_, blk, 0, stream>>>(Qc, Kc, top_vals, top_idx, b0 * D_);
  }
  shifts_kernel<<<TOPK_, blk, 0, stream>>>(top_idx, shifts);
  softmax_kernel<<<CH_ / 256, blk, 0, stream>>>(top_vals, weights);

  {
    dim3 gp(L_ / 128, D_ / 128, B_);
    gemm_mfma<1, false, false><<<gp, blk, 0, stream>>>(
        Wv, value, bvp, VcAgg, 0, bXS, cQS, L_);
  }
  agg_kernel<<<CH_, blk, 0, stream>>>(VcAgg, weights, shifts);

  if (!bounce) {
    dim3 go(D_ / 128, L_ / 128, B_);    // (4, 24, 16)
    gemm_mfma<1, true, true><<<go, blk, 0, stream>>>(
        VcAgg, Wo, bo, out, cQS, 0, bXS, D_);
  } else {
    for (int b = 0; b < B_; ++b) {
      hipMemcpyAsync(bounce_buf, VcAgg + (size_t)b * D_ * L_, BOUNCE_BYTES,
                     hipMemcpyDeviceToDevice, stream);
      dim3 go(D_ / 128, L_ / 128, 1);
      gemm_mfma<1, true, true><<<go, blk, 0, stream>>>(
          bounce_buf, Wo, bo, out + (size_t)b * L_ * D_, 0, 0, 0, D_);
    }
  }
  (void)in_sizes; (void)n_in; (void)out_size;
}

// Round 18
// 962.707 us; speedup vs baseline: 1.4683x; 1.0932x over previous
//
#include <hip/hip_runtime.h>
#include <hip/hip_bf16.h>
#include <math.h>

#define B_ 16
#define L_ 3072
#define D_ 512
#define CH_ (B_ * D_)   // 8192 channels
#define TOPK_ 40
#define NCAND_ 64       // candidate slots per channel
#define CFLOOR_ 52      // candidate count floor (>= RFN_ always)
#define RFN_ 24         // candidates refined exactly in f64 (rounds 3/4 proven)

typedef unsigned short ushort_t;
typedef unsigned int uint_t;
typedef __attribute__((ext_vector_type(8))) short bh8;   // 8 bf16 (4 VGPRs)
typedef __attribute__((ext_vector_type(4))) float f4;    // 4 f32 acc
typedef __attribute__((ext_vector_type(4))) int i4;      // 16B vector

__device__ __forceinline__ uint_t cvt_pk_bf16(float a, float b) {
  uint_t r;
  asm("v_cvt_pk_bf16_f32 %0, %1, %2" : "=v"(r) : "v"(a), "v"(b));
  return r;  // lo ushort = bf16(a), hi ushort = bf16(b)
}

// LDS byte-address swizzles (involutions; preserve 16B alignment)
__device__ __forceinline__ int swzq(int b) { return b ^ (((b >> 7) & 3) << 4); }
__device__ __forceinline__ int swzk(int b) { return b ^ (((b >> 9) & 7) << 4); }

// ---------------------------------------------------------------------------
// MFMA GEMM core, 128x128 tile, 4 waves. C[m][n] = sum_k A[m][k] B[n][k]+bias.
// NPASS=1: plain bf16 (V proj, out GEMM — round-4/8 PROVEN, absmax floor).
// NPASS=6: 3-way split-bf16 (h/m/l, Sterbenz-exact residuals; products
//   hh+hm+mh+mm+hl+lh) -> dP ~1.5e-6, round-15 PROVEN on HW (absmax floor).
// ---------------------------------------------------------------------------
template <int NPASS, int BK, int ST>
__device__ __forceinline__ void stage_rows(const float* __restrict__ g0,
                                           ushort_t* __restrict__ Hh,
                                           ushort_t* __restrict__ Hm,
                                           ushort_t* __restrict__ Hl,
                                           int tid) {
  const int row = tid >> 1;
  const int cb = (tid & 1) * (BK / 2);
  const float* g = g0 + (size_t)row * 512 + cb;
  ushort_t* ph = Hh + row * ST + cb;
  ushort_t* pm = Hm + row * ST + cb;
  ushort_t* pl = Hl + row * ST + cb;
#pragma unroll
  for (int p = 0; p < BK / 8; ++p) {
    float4 v = *(const float4*)(g + 4 * p);
    uint_t h01 = cvt_pk_bf16(v.x, v.y);
    uint_t h23 = cvt_pk_bf16(v.z, v.w);
    *(uint2*)(ph + 4 * p) = make_uint2(h01, h23);
    if (NPASS >= 3) {
      float x0 = __builtin_bit_cast(float, h01 << 16);
      float x1 = __builtin_bit_cast(float, h01 & 0xFFFF0000u);
      float x2 = __builtin_bit_cast(float, h23 << 16);
      float x3 = __builtin_bit_cast(float, h23 & 0xFFFF0000u);
      float r0 = v.x - x0, r1 = v.y - x1, r2 = v.z - x2, r3 = v.w - x3;
      uint_t m01 = cvt_pk_bf16(r0, r1);
      uint_t m23 = cvt_pk_bf16(r2, r3);
      if (NPASS == 3) {
        *(uint2*)(pl + 4 * p) = make_uint2(m01, m23);
      } else {  // NPASS == 6: store m, then exact third level l
        *(uint2*)(pm + 4 * p) = make_uint2(m01, m23);
        float y0 = __builtin_bit_cast(float, m01 << 16);
        float y1 = __builtin_bit_cast(float, m01 & 0xFFFF0000u);
        float y2 = __builtin_bit_cast(float, m23 << 16);
        float y3 = __builtin_bit_cast(float, m23 & 0xFFFF0000u);
        uint_t l01 = cvt_pk_bf16(r0 - y0, r1 - y1);
        uint_t l23 = cvt_pk_bf16(r2 - y2, r3 - y3);
        *(uint2*)(pl + 4 * p) = make_uint2(l01, l23);
      }
    }
  }
}

template <int NPASS, bool ATR, bool BIAS_N>
__device__ __forceinline__ void gemm_core(const float* __restrict__ Asrc,
                                          const float* __restrict__ Bsrc,
                                          const float* __restrict__ bias,
                                          float* __restrict__ Cb,
                                          int n0, int m0, int cld,
                                          ushort_t* Ah, ushort_t* Bh,
                                          ushort_t* Am, ushort_t* Bm,
                                          ushort_t* Al, ushort_t* Bl) {
  constexpr int BK = (NPASS == 1) ? 64 : 32;
  constexpr int ST = (NPASS == 1) ? 72 : 40;
  const int tid = threadIdx.x;
  const int lane = tid & 63, w = tid >> 6;
  const int wr = w >> 1, wc = w & 1;
  const int lj = lane & 15, lg = lane >> 4;

  f4 acc[4][4];
#pragma unroll
  for (int fm = 0; fm < 4; ++fm)
#pragma unroll
    for (int fn = 0; fn < 4; ++fn) acc[fm][fn] = (f4){0.f, 0.f, 0.f, 0.f};

  for (int kc = 0; kc < 512; kc += BK) {
    if (!ATR) {
      stage_rows<NPASS, BK, ST>(Asrc + (size_t)m0 * 512 + kc, Ah, Am, Al, tid);
    } else {
      constexpr int TPC = 256 / BK;
      constexpr int TC  = 128 / TPC;
      const int jl = tid / TPC, ts = tid % TPC;
      const float* g = Asrc + (size_t)(kc + jl) * L_ + m0 + ts * TC;
#pragma unroll
      for (int p = 0; p < TC / 4; ++p) {
        float4 v = *(const float4*)(g + 4 * p);
        uint_t h01 = cvt_pk_bf16(v.x, v.y);
        uint_t h23 = cvt_pk_bf16(v.z, v.w);
        int t = ts * TC + 4 * p;
        Ah[(t + 0) * ST + jl] = (ushort_t)(h01 & 0xFFFFu);
        Ah[(t + 1) * ST + jl] = (ushort_t)(h01 >> 16);
        Ah[(t + 2) * ST + jl] = (ushort_t)(h23 & 0xFFFFu);
        Ah[(t + 3) * ST + jl] = (ushort_t)(h23 >> 16);
      }
    }
    stage_rows<NPASS, BK, ST>(Bsrc + (size_t)n0 * 512 + kc, Bh, Bm, Bl, tid);
    __syncthreads();

#pragma unroll
    for (int ks = 0; ks < BK / 32; ++ks) {
      const int kk = ks * 32 + 8 * lg;
      bh8 af[4], bf[4];
#pragma unroll
      for (int f = 0; f < 4; ++f)
        af[f] = *(const bh8*)&Ah[(64 * wr + 16 * f + lj) * ST + kk];
#pragma unroll
      for (int f = 0; f < 4; ++f)
        bf[f] = *(const bh8*)&Bh[(64 * wc + 16 * f + lj) * ST + kk];
#pragma unroll
      for (int fm = 0; fm < 4; ++fm)
#pragma unroll
        for (int fn = 0; fn < 4; ++fn)
          acc[fm][fn] = __builtin_amdgcn_mfma_f32_16x16x32_bf16(af[fm], bf[fn],
                                                                acc[fm][fn], 0, 0, 0);
      if (NPASS >= 3) {
        bh8 bl_[4];
#pragma unroll
        for (int f = 0; f < 4; ++f)
          bl_[f] = *(const bh8*)&Bl[(64 * wc + 16 * f + lj) * ST + kk];
        bh8 al_[4];
#pragma unroll
        for (int f = 0; f < 4; ++f)
          al_[f] = *(const bh8*)&Al[(64 * wr + 16 * f + lj) * ST + kk];
        if (NPASS == 3) {
#pragma unroll
          for (int fm = 0; fm < 4; ++fm)
#pragma unroll
            for (int fn = 0; fn < 4; ++fn)
              acc[fm][fn] = __builtin_amdgcn_mfma_f32_16x16x32_bf16(af[fm], bl_[fn],
                                                                    acc[fm][fn], 0, 0, 0);
#pragma unroll
          for (int fm = 0; fm < 4; ++fm)
#pragma unroll
            for (int fn = 0; fn < 4; ++fn)
              acc[fm][fn] = __builtin_amdgcn_mfma_f32_16x16x32_bf16(al_[fm], bf[fn],
                                                                    acc[fm][fn], 0, 0, 0);
        } else {
          bh8 am_[4], bm_[4];
#pragma unroll
          for (int f = 0; f < 4; ++f)
            am_[f] = *(const bh8*)&Am[(64 * wr + 16 * f + lj) * ST + kk];
#pragma unroll
          for (int f = 0; f < 4; ++f)
            bm_[f] = *(const bh8*)&Bm[(64 * wc + 16 * f + lj) * ST + kk];
#pragma unroll
          for (int fm = 0; fm < 4; ++fm)
#pragma unroll
            for (int fn = 0; fn < 4; ++fn)
              acc[fm][fn] = __builtin_amdgcn_mfma_f32_16x16x32_bf16(af[fm], bm_[fn],
                                                                    acc[fm][fn], 0, 0, 0);
#pragma unroll
          for (int fm = 0; fm < 4; ++fm)
#pragma unroll
            for (int fn = 0; fn < 4; ++fn)
              acc[fm][fn] = __builtin_amdgcn_mfma_f32_16x16x32_bf16(am_[fm], bf[fn],
                                                                    acc[fm][fn], 0, 0, 0);
#pragma unroll
          for (int fm = 0; fm < 4; ++fm)
#pragma unroll
            for (int fn = 0; fn < 4; ++fn)
              acc[fm][fn] = __builtin_amdgcn_mfma_f32_16x16x32_bf16(am_[fm], bm_[fn],
                                                                    acc[fm][fn], 0, 0, 0);
#pragma unroll
          for (int fm = 0; fm < 4; ++fm)
#pragma unroll
            for (int fn = 0; fn < 4; ++fn)
              acc[fm][fn] = __builtin_amdgcn_mfma_f32_16x16x32_bf16(af[fm], bl_[fn],
                                                                    acc[fm][fn], 0, 0, 0);
#pragma unroll
          for (int fm = 0; fm < 4; ++fm)
#pragma unroll
            for (int fn = 0; fn < 4; ++fn)
              acc[fm][fn] = __builtin_amdgcn_mfma_f32_16x16x32_bf16(al_[fm], bf[fn],
                                                                    acc[fm][fn], 0, 0, 0);
        }
      }
    }
    __syncthreads();
  }

#pragma unroll
  for (int fm = 0; fm < 4; ++fm) {
    const int mrow = m0 + 64 * wr + 16 * fm + 4 * lg;
#pragma unroll
    for (int fn = 0; fn < 4; ++fn) {
      const int ncol = n0 + 64 * wc + 16 * fn + lj;
      const float bn = BIAS_N ? bias[ncol] : 0.0f;
#pragma unroll
      for (int r = 0; r < 4; ++r) {
        float val = acc[fm][fn][r] + (BIAS_N ? bn : bias[mrow + r]);
        Cb[(size_t)(mrow + r) * cld + ncol] = val;
      }
    }
  }
}

// generic kernel (V proj NPASS1, out GEMM NPASS1-ATR)
template <int NPASS, bool ATR, bool BIAS_N>
__global__ __launch_bounds__(256) void gemm_mfma(const float* __restrict__ Ap,
                                                 const float* __restrict__ Bp,
                                                 const float* __restrict__ bias,
                                                 float* __restrict__ Cp,
                                                 long aBS, long bBS, long cBS,
                                                 int cld) {
  constexpr int ST = (NPASS == 1) ? 72 : 40;
  __shared__ ushort_t Ah[128 * ST];
  __shared__ ushort_t Bh[128 * ST];
  __shared__ ushort_t Al[(NPASS >= 3) ? 128 * ST : 8];
  __shared__ ushort_t Bl[(NPASS >= 3) ? 128 * ST : 8];
  __shared__ ushort_t Am[(NPASS == 6) ? 128 * ST : 8];
  __shared__ ushort_t Bm[(NPASS == 6) ? 128 * ST : 8];
  gemm_core<NPASS, ATR, BIAS_N>(Ap + (size_t)blockIdx.z * aBS,
                                Bp + (size_t)blockIdx.z * bBS, bias,
                                Cp + (size_t)blockIdx.z * cBS,
                                blockIdx.x * 128, blockIdx.y * 128, cld,
                                Ah, Bh, Am, Bm, Al, Bl);
}

// merged Q+K NPASS=6 projection (z-split); per-element math identical to the
// round-15 passing gemm_mfma<6> -> Qc/Kc bit-identical.
__global__ __launch_bounds__(256) void gemm6_qk(const float* __restrict__ Xq,
                                                const float* __restrict__ Xk,
                                                const float* __restrict__ Wq_,
                                                const float* __restrict__ Wk_,
                                                const float* __restrict__ bq_,
                                                const float* __restrict__ bk_,
                                                float* __restrict__ Pq,
                                                float* __restrict__ Pk,
                                                int nbb) {
  __shared__ ushort_t Ah[128 * 40];
  __shared__ ushort_t Bh[128 * 40];
  __shared__ ushort_t Al[128 * 40];
  __shared__ ushort_t Bl[128 * 40];
  __shared__ ushort_t Am[128 * 40];
  __shared__ ushort_t Bm[128 * 40];
  const int z = blockIdx.z;
  const bool isK = (z >= nbb);
  const int b = isK ? (z - nbb) : z;
  const float* Asrc = isK ? Wk_ : Wq_;
  const float* Bsrc = (isK ? Xk : Xq) + (size_t)b * L_ * D_;
  const float* bias = isK ? bk_ : bq_;
  float* Cb = (isK ? Pk : Pq) + (size_t)b * D_ * L_;
  gemm_core<6, false, false>(Asrc, Bsrc, bias, Cb,
                             blockIdx.x * 128, blockIdx.y * 128, L_,
                             Ah, Bh, Am, Bm, Al, Bl);
}

// ---------------------------------------------------------------------------
// FUSED MFMA autocorrelation + candidate selection + f64 refinement + top-40.
// (Round-17 structure, PASSED at absmax floor — unchanged.)
// ---------------------------------------------------------------------------
__device__ __forceinline__ void ac_kloop8(const char* __restrict__ qb,
                                          const char* __restrict__ kb,
                                          const int* __restrict__ aswz,
                                          int bbyte, int tbase, f4 acc[8]) {
#pragma unroll
  for (int it = 0; it < 6; ++it) {
    const int t512 = tbase + it * 512;
    const int b512 = bbyte + t512;
    const int msk = ((b512 >> 9) & 7) << 4;
    const int e0 = b512 ^ msk;
    const int e1 = (b512 + 64) ^ msk;
#pragma unroll
    for (int u = 0; u < 8; ++u) {
      i4 w0 = *(const i4*)(qb + (aswz[2 * u] + t512));
      i4 w1 = *(const i4*)(qb + (aswz[2 * u + 1] + t512));
      uint_t w[8] = { (uint_t)w0.x, (uint_t)w0.y, (uint_t)w0.z, (uint_t)w0.w,
                      (uint_t)w1.x, (uint_t)w1.y, (uint_t)w1.z, (uint_t)w1.w };
      uint_t s[7];
#pragma unroll
      for (int i = 0; i < 7; ++i)
        s[i] = (uint_t)((((unsigned long long)w[i + 1] << 32) | w[i]) >> 16);
      const int bb = ((u & 1) ? e1 : e0) + 128 * (u >> 1);
      bh8 Bf = *(const bh8*)(kb + bb);
#pragma unroll
      for (int e = 0; e < 8; ++e) {
        const int ro = e >> 1;
        i4 ai;
        if ((e & 1) == 0)
          ai = (i4){ (int)w[ro], (int)w[ro + 1], (int)w[ro + 2], (int)w[ro + 3] };
        else
          ai = (i4){ (int)s[ro], (int)s[ro + 1], (int)s[ro + 2], (int)s[ro + 3] };
        bh8 Af = __builtin_bit_cast(bh8, ai);
        acc[e] = __builtin_amdgcn_mfma_f32_16x16x32_bf16(Af, Bf, acc[e], 0, 0, 0);
      }
    }
  }
}

__global__ __launch_bounds__(256) void cand_refine_kernel(const float* __restrict__ Q,
                                                          const float* __restrict__ K,
                                                          double* __restrict__ top_vals,
                                                          int* __restrict__ top_idx,
                                                          int c0) {
  // phase A: [0,6912) q bf16 (swz) | [6912,18688) k bf16 (swz)
  // post-kloop: ac1 f32 [0,12288) | ac2 f32 [12288,24576)
  // phase C:   qf f32 [0,12292) (incl. qf[L] pad) | kf f32 [12304,24592)
  __shared__ __align__(16) char smem[24608];
  __shared__ float redf[8];
  __shared__ int   redi[4];
  __shared__ int   cnt_s;
  __shared__ float cv[NCAND_];
  __shared__ int   ci[NCAND_];
  __shared__ float sv[TOPK_];
  __shared__ int   si[TOPK_];
  __shared__ double refv[RFN_];
  char* kbase = smem + 6912;
  float* ac1 = (float*)smem;
  float* ac2 = (float*)(smem + 12288);
  const int c = blockIdx.x;
  const int tid = threadIdx.x;
  const float* Qp = Q + (size_t)c * L_;
  const float* Kp = K + (size_t)c * L_;

  // ---- Phase A staging: f32 -> bf16 (cvt_pk), swizzled stores ----
  for (int x8 = tid; x8 < 432; x8 += 256) {
    int x = x8 * 8; int src = x - (x >= L_ ? L_ : 0);
    float4 f0 = *(const float4*)(Qp + src);
    float4 f1 = *(const float4*)(Qp + src + 4);
    i4 pk = { (int)cvt_pk_bf16(f0.x, f0.y), (int)cvt_pk_bf16(f0.z, f0.w),
              (int)cvt_pk_bf16(f1.x, f1.y), (int)cvt_pk_bf16(f1.z, f1.w) };
    *(i4*)(smem + swzq(16 * x8)) = pk;
  }
  for (int x8 = tid; x8 < 736; x8 += 256) {
    int x = x8 * 8; int src = x - 2816 + (x < 2816 ? L_ : 0);
    float4 f0 = *(const float4*)(Kp + src);
    float4 f1 = *(const float4*)(Kp + src + 4);
    i4 pk = { (int)cvt_pk_bf16(f0.x, f0.y), (int)cvt_pk_bf16(f0.z, f0.w),
              (int)cvt_pk_bf16(f1.x, f1.y), (int)cvt_pk_bf16(f1.z, f1.w) };
    *(i4*)(kbase + swzk(16 * x8)) = pk;
  }
  __syncthreads();

  const int lane = tid & 63, fg = tid >> 6;
  const int lg = lane >> 4, lj = lane & 15;
  const int fh = fg & 1;          // f half: f = 8*fh + e
  const int th = fg >> 1;         // t half: tbase = th*3072 bytes
  const int abyte = 16 * lg + 32 * lj + 16 * fh;
  const int jvalid = (lj < 12) ? 1 : 0;
  const int bbyte = 5632 + 16 * lg - (jvalid ? 512 * lj : 0);
  const int tbase = th * 3072;

  int aswz[16];
#pragma unroll
  for (int u = 0; u < 8; ++u) {
    aswz[2 * u]     = swzq(abyte + 64 * u);
    aswz[2 * u + 1] = swzq(abyte + 64 * u + 16);
  }

  f4 acc[8];
#pragma unroll
  for (int e = 0; e < 8; ++e) acc[e] = (f4){0.f, 0.f, 0.f, 0.f};

  ac_kloop8(smem, kbase, aswz, bbyte, tbase, acc);

  __syncthreads();   // all kloop q/k reads done before ac overlays them

  if (jvalid) {
    float* dst = th ? ac2 : ac1;
#pragma unroll
    for (int e = 0; e < 8; ++e) {
      int f = 8 * fh + e;
#pragma unroll
      for (int r = 0; r < 4; ++r) {
        int g = f + 16 * (4 * lg + r);      // fine lag in [0,256)
        dst[lj + 12 * g] = acc[e][r];       // tau = g + 256*lj
      }
    }
  }
  __syncthreads();

  float v[12];
#pragma unroll
  for (int it = 0; it < 12; ++it)
    v[it] = ac1[tid + 256 * it] + ac2[tid + 256 * it];  // (th0 + th1) order

  // block max
  float lm = v[0];
#pragma unroll
  for (int it = 1; it < 12; ++it) lm = fmaxf(lm, v[it]);
  for (int o = 32; o; o >>= 1) lm = fmaxf(lm, __shfl_down(lm, o));
  if ((tid & 63) == 0) redf[tid >> 6] = lm;
  __syncthreads();
  if (tid == 0) redf[4] = fmaxf(fmaxf(redf[0], redf[1]), fmaxf(redf[2], redf[3]));
  __syncthreads();
  const float Tmax = redf[4];

  auto bcount = [&](float T) -> int {
    int lc = 0;
#pragma unroll
    for (int it = 0; it < 12; ++it) lc += (v[it] > T) ? 1 : 0;
    for (int o = 32; o; o >>= 1) lc += __shfl_down(lc, o);
    __syncthreads();
    if ((tid & 63) == 0) redi[tid >> 6] = lc;
    __syncthreads();
    return redi[0] + redi[1] + redi[2] + redi[3];
  };

  float lo = Tmax - 128.0f;
  int cl = bcount(lo);
  for (int wd = 1; wd <= 5 && cl < CFLOOR_; ++wd) {
    lo = Tmax - 128.0f * (float)(1 << wd); cl = bcount(lo);
  }
  float hi = Tmax, T = lo;
  int cT = cl;
  for (int i = 0; i < 26 && cT > NCAND_; ++i) {
    float mid = 0.5f * (lo + hi);
    int cm = bcount(mid);
    if (cm >= CFLOOR_) { lo = mid; T = mid; cT = cm; } else hi = mid;
  }

  if (tid == 0) cnt_s = 0;
  __syncthreads();
#pragma unroll
  for (int it = 0; it < 12; ++it) {
    if (v[it] > T) {
      int pos = atomicAdd(&cnt_s, 1);
      if (pos < NCAND_) {
        int m = tid + 256 * it;
        int g = m / 12, j = m - 12 * g;
        cv[pos] = v[it];
        ci[pos] = g + 256 * j;
      }
    }
  }
  __syncthreads();
  const int cnt = cnt_s < NCAND_ ? cnt_s : NCAND_;

  // ---- Phase B (wave 0: rank-based f32 top-40) || C-staging (waves 1-3) ---
  float* qf = (float*)smem;
  float* kf = (float*)(smem + 12304);
  if (tid >= 64) {
    for (int i = (tid - 64) * 4; i < L_; i += 768) {
      *(float4*)&qf[i] = *(const float4*)(Qp + i);
      *(float4*)&kf[i] = *(const float4*)(Kp + i);
    }
    if (tid == 64) qf[L_] = qf[0];   // circular pad for phase-C pair reads
  } else {
    float vi = (tid < cnt) ? cv[tid] : -1e30f;
    int   ii = (tid < cnt) ? ci[tid] : (1 << 30);
    int rank = 0;
#pragma unroll 8
    for (int j = 0; j < 64; ++j) {
      float vj = __shfl(vi, j);
      int   ij = __shfl(ii, j);
      rank += ((vj > vi) || (vj == vi && ij < ii)) ? 1 : 0;
    }
    if (rank < TOPK_) { sv[rank] = vi; si[rank] = (ii < L_) ? ii : 0; }
  }
  __syncthreads();

  // ---- Phase C: exact f64 ac for top-RFN_, one WAVE per candidate, 2-wide -
  for (int r = fg; r < RFN_; r += 4) {
    const int tau = si[r];
    double a = 0.0;
#pragma unroll 4
    for (int u = 0; u < 24; ++u) {
      int t = 2 * lane + 128 * u;
      int qi = t + tau; qi -= (qi >= L_) ? L_ : 0;
      float q0 = qf[qi], q1 = qf[qi + 1];
      float2 kv = *(const float2*)&kf[t];   // t even -> 8B aligned
      a = fma((double)q0, (double)kv.x, a);
      a = fma((double)q1, (double)kv.y, a);
    }
#pragma unroll
    for (int o = 32; o; o >>= 1) a += __shfl_down(a, o);
    if (lane == 0) refv[r] = a;
  }
  __syncthreads();

  // ---- Phase D: rank-based f64 sort of refined -> ranks 0..RFN_-1;
  //      ranks RFN_..39 from f32 order (rounds 3/4 proven harmless) ----
  double* out_v = top_vals + (size_t)(c0 + c) * TOPK_;
  int*    out_i = top_idx  + (size_t)(c0 + c) * TOPK_;
  if (tid < 64) {
    double dv = (tid < RFN_) ? refv[tid] : -1e300;
    int    di = (tid < RFN_) ? si[tid]   : (1 << 30);
    int rank = 0;
#pragma unroll 8
    for (int j = 0; j < RFN_; ++j) {
      double dj = __shfl(dv, j);
      int    ij = __shfl(di, j);
      rank += ((dj > dv) || (dj == dv && ij < di)) ? 1 : 0;
    }
    if (tid < RFN_) { out_v[rank] = dv; out_i[rank] = di; }
    if (tid >= RFN_ && tid < TOPK_) {
      out_v[tid] = (double)sv[tid];
      out_i[tid] = si[tid];
    }
  }
}

// ---------------------------------------------------------------------------
__global__ __launch_bounds__(256) void shifts_kernel(const int* __restrict__ top_idx,
                                                     int* __restrict__ shifts) {
  const int k = blockIdx.x;
  __shared__ double sred[256];
  double s = 0.0;
  for (int c = threadIdx.x; c < CH_; c += 256) s += (double)top_idx[(size_t)c * TOPK_ + k];
  sred[threadIdx.x] = s;
  __syncthreads();
  for (int o = 128; o > 0; o >>= 1) {
    if (threadIdx.x < o) sred[threadIdx.x] += sred[threadIdx.x + o];
    __syncthreads();
  }
  if (threadIdx.x == 0) shifts[k] = (int)((float)(sred[0] / (double)CH_));
}

__global__ __launch_bounds__(256) void softmax_kernel(const double* __restrict__ top_vals,
                                                      float* __restrict__ weights) {
  const int c = blockIdx.x * 256 + threadIdx.x;
  const double* v = top_vals + (size_t)c * TOPK_;
  double m = v[0];
  for (int k = 1; k < TOPK_; ++k) m = fmax(m, v[k]);
  double sum = 0.0;
  for (int k = 0; k < TOPK_; ++k) sum += exp(v[k] - m);
  double inv = 1.0 / sum;
  for (int k = 0; k < TOPK_; ++k)
    weights[(size_t)c * TOPK_ + k] = (float)(exp(v[k] - m) * inv);
}

// agg[c][t] = sum_k w[c][k] * V[c][(t+shift[k]) mod L], in place.
// Round-18: inner loop back to STRIDE-1 thread->t mapping (round-8 proven):
// lane l reads v_s[t0+l+s_k] -> consecutive banks -> conflict-free (was
// t=tid*4 float4: bank stride 4 -> 8-way conflict on all 40x4 taps).
// Per-output fmaf chain over k unchanged -> BIT-IDENTICAL output.
__global__ __launch_bounds__(256) void agg_kernel(float* __restrict__ Vc,
                                                  const float* __restrict__ weights,
                                                  const int* __restrict__ shifts) {
  const int c = blockIdx.x;
  __shared__ float v_s[L_];
  __shared__ float w_s[TOPK_];
  __shared__ int   s_s[TOPK_];
  float* row = Vc + (size_t)c * L_;
  for (int i = threadIdx.x * 4; i < L_; i += 1024)
    *(float4*)&v_s[i] = *(const float4*)(row + i);
  if (threadIdx.x < TOPK_) {
    w_s[threadIdx.x] = weights[(size_t)c * TOPK_ + threadIdx.x];
    s_s[threadIdx.x] = shifts[threadIdx.x];
  }
  __syncthreads();
  for (int t = threadIdx.x; t < L_; t += 256) {
    float sum = 0.0f;
#pragma unroll
    for (int k = 0; k < TOPK_; ++k) {
      int idx = t + s_s[k];
      if (idx >= L_) idx -= L_;
      sum = fmaf(w_s[k], v_s[idx], sum);
    }
    row[t] = sum;
  }
}

// ---------------------------------------------------------------------------
extern "C" void kernel_launch(void* const* d_in, const int* in_sizes, int n_in,
                              void* d_out, int out_size, void* d_ws, size_t ws_size,
                              hipStream_t stream) {
  const float* query = (const float*)d_in[0];
  const float* key   = (const float*)d_in[1];
  const float* value = (const float*)d_in[2];
  const float* Wq = (const float*)d_in[3];
  const float* bq = (const float*)d_in[4];
  const float* Wk = (const float*)d_in[5];
  const float* bk = (const float*)d_in[6];
  const float* Wv = (const float*)d_in[7];
  const float* bvp = (const float*)d_in[8];
  const float* Wo = (const float*)d_in[9];
  const float* bo = (const float*)d_in[10];
  float* out = (float*)d_out;
  char* ws = (char*)d_ws;

  auto al = [](size_t x) { return (x + 255) & ~(size_t)255; };
  size_t off = 0;
  const size_t tv_off = off; off = al(off + (size_t)CH_ * TOPK_ * 8);
  const size_t ti_off = off; off = al(off + (size_t)CH_ * TOPK_ * 4);
  const size_t w_off  = off; off = al(off + (size_t)CH_ * TOPK_ * 4);
  const size_t sh_off = off; off = al(off + (size_t)TOPK_ * 4);
  const size_t small_end = off;                       // ~5.3 MB

  const size_t QK1   = (size_t)D_ * L_ * 4;           // 6.29 MB f32, one batch
  const size_t PBQK  = al(2 * QK1);                   // ~12.6 MB per batch
  const size_t AGG_BYTES    = (size_t)CH_ * L_ * 4;   // 96 MB
  const size_t BOUNCE_BYTES = (size_t)D_ * L_ * 4;    // 6 MB

  int nb; bool bounce;
  if (ws_size >= small_end + AGG_BYTES + PBQK) {
    bounce = false;
    size_t n = (ws_size - small_end - AGG_BYTES) / PBQK;
    nb = (int)(n > 16 ? 16 : n);
  } else {
    bounce = true;
    size_t rem = (ws_size > small_end + BOUNCE_BYTES) ? (ws_size - small_end - BOUNCE_BYTES) : 0;
    size_t n = rem / PBQK; nb = (int)(n > 16 ? 16 : n);
    if (nb < 1) nb = 1;
  }

  double* top_vals = (double*)(ws + tv_off);
  int*    top_idx  = (int*)(ws + ti_off);
  float*  weights  = (float*)(ws + w_off);
  int*    shifts   = (int*)(ws + sh_off);

  float* VcAgg;
  float* bounce_buf = nullptr;
  size_t qk_off;
  if (!bounce) {
    VcAgg = (float*)(ws + small_end);
    qk_off = small_end + al(AGG_BYTES);
  } else {
    bounce_buf = (float*)(ws + small_end);
    qk_off = small_end + al(BOUNCE_BYTES);
    VcAgg = (float*)d_out;
  }
  float* Qc = (float*)(ws + qk_off);
  float* Kc = (float*)(ws + qk_off + al((size_t)nb * QK1));

  dim3 blk(256);
  const long bXS = (long)L_ * D_;   // batch stride of inputs / out
  const long cQS = (long)D_ * L_;   // batch stride of channel-major tensors

  for (int b0 = 0; b0 < B_; b0 += nb) {
    int nbb = (B_ - b0 < nb) ? (B_ - b0) : nb;
    dim3 gp(L_ / 128, D_ / 128, 2 * nbb);   // (24, 4, 2*nbb)
    gemm6_qk<<<gp, blk, 0, stream>>>(query + (size_t)b0 * L_ * D_,
                                     key   + (size_t)b0 * L_ * D_,
                                     Wq, Wk, bq, bk, Qc, Kc, nbb);
    cand_refine_kernel<<<nbb * D_, blk, 0, stream>>>(Qc, Kc, top_vals, top_idx, b0 * D_);
  }
  shifts_kernel<<<TOPK_, blk, 0, stream>>>(top_idx, shifts);
  softmax_kernel<<<CH_ / 256, blk, 0, stream>>>(top_vals, weights);

  {
    dim3 gp(L_ / 128, D_ / 128, B_);
    gemm_mfma<1, false, false><<<gp, blk, 0, stream>>>(
        Wv, value, bvp, VcAgg, 0, bXS, cQS, L_);
  }
  agg_kernel<<<CH_, blk, 0, stream>>>(VcAgg, weights, shifts);

  if (!bounce) {
    dim3 go(D_ / 128, L_ / 128, B_);    // (4, 24, 16)
    gemm_mfma<1, true, true><<<go, blk, 0, stream>>>(
        VcAgg, Wo, bo, out, cQS, 0, bXS, D_);
  } else {
    for (int b = 0; b < B_; ++b) {
      hipMemcpyAsync(bounce_buf, VcAgg + (size_t)b * D_ * L_, BOUNCE_BYTES,
                     hipMemcpyDeviceToDevice, stream);
      dim3 go(D_ / 128, L_ / 128, 1);
      gemm_mfma<1, true, true><<<go, blk, 0, stream>>>(
          bounce_buf, Wo, bo, out + (size_t)b * L_ * D_, 0, 0, 0, D_);
    }
  }
  (void)in_sizes; (void)n_in; (void)out_size;
}